// Round 11
// baseline (244.261 us; speedup 1.0000x reference)
//
#include <hip/hip_runtime.h>
#include <hip/hip_bf16.h>
#include <cstdint>
#include <cstddef>

// CausalSelfAttention: B=4, T=2048, C=1024, H=16, hs=64 (fp32 in/out, bf16 MFMA compute)
//
// Pipeline: x->bf16 | W^T bf16 | GEMM1 (qkv; V written transposed in epilogue)
//           | flash attn (32x32 MFMA, swapped operands) | GEMM2
//
// Workspace layout (96 MiB):
//   [0,16M)   x_bf16 (GEMM1 input), then reused as Vt[b][h][64][2048]
//   [16M,22M) W_attn^T bf16
//   [24M,26M) W_proj^T bf16
//   [32M,80M) qkv bf16 (8192 x 3072; V-section cols 2048.. unwritten)
//   [80M,96M) y bf16   (8192 x 1024)

typedef unsigned short ushort_t;
typedef __attribute__((ext_vector_type(8))) short short8;
typedef __attribute__((ext_vector_type(4))) float f32x4;
typedef __attribute__((ext_vector_type(16))) float f32x16;

#define AS1 __attribute__((address_space(1)))
#define AS3 __attribute__((address_space(3)))

#if __has_builtin(__builtin_amdgcn_exp2f)
#define EXP2(x) __builtin_amdgcn_exp2f(x)
#else
#define EXP2(x) exp2f(x)
#endif

__device__ __forceinline__ ushort_t f2bf(float f) {
  union { float f; unsigned u; } c; c.f = f;
  unsigned u = c.u;
  return (ushort_t)((u + 0x7FFFu + ((u >> 16) & 1u)) >> 16);  // RNE
}

// v_cvt_pk_bf16_f32: lo16 = bf16(a), hi16 = bf16(b)
__device__ __forceinline__ unsigned cvt_pk_bf16(float a, float b) {
  unsigned r;
  asm("v_cvt_pk_bf16_f32 %0, %1, %2" : "=v"(r) : "v"(a), "v"(b));
  return r;
}

// ---------------- fp32 -> bf16 elementwise (8 elems/thread) ----------------
__global__ __launch_bounds__(256) void k_f32_to_bf16(const float* __restrict__ in,
                                                     ushort_t* __restrict__ out) {
  const size_t i = ((size_t)blockIdx.x * 256 + threadIdx.x) * 8;
  f32x4 a = *(const f32x4*)(in + i);
  f32x4 b = *(const f32x4*)(in + i + 4);
  short8 o;
  o[0] = (short)f2bf(a[0]); o[1] = (short)f2bf(a[1]);
  o[2] = (short)f2bf(a[2]); o[3] = (short)f2bf(a[3]);
  o[4] = (short)f2bf(b[0]); o[5] = (short)f2bf(b[1]);
  o[6] = (short)f2bf(b[2]); o[7] = (short)f2bf(b[3]);
  *(short8*)(out + i) = o;
}

// ------------- fp32 (R x C) -> bf16 transposed (C x R), LDS-tiled ----------
__global__ __launch_bounds__(256) void k_transpose_bf16(const float* __restrict__ in,
                                                        ushort_t* __restrict__ out,
                                                        int R, int C) {
  __shared__ float tile[32][33];
  const int tx = threadIdx.x & 31, ty = threadIdx.x >> 5;  // 32x8
  const int c0 = blockIdx.x * 32, r0 = blockIdx.y * 32;
#pragma unroll
  for (int i = 0; i < 32; i += 8)
    tile[ty + i][tx] = in[(size_t)(r0 + ty + i) * C + c0 + tx];
  __syncthreads();
#pragma unroll
  for (int i = 0; i < 32; i += 8)
    out[(size_t)(c0 + ty + i) * R + r0 + tx] = f2bf(tile[tx][ty + i]);
}

// ---------------- bf16 GEMM: C[M,N] = A[M,K] * Bt[N,K]^T -------------------
// OUTMODE: 0 = fp32 out; 1 = bf16 out; 2 = bf16 out for cols<2048 plus
// V-transpose epilogue (cols>=2048 written as Vt[b][h][d][t]).
// XCD-aware bijective block swizzle (T1/m204): contiguous grid chunks per XCD
// so same-by neighbors (sharing the A-panel) hit the same L2.
template <int OUTMODE>
__global__ __launch_bounds__(256) void k_gemm_bt(const ushort_t* __restrict__ A,
                                                 const ushort_t* __restrict__ Bt,
                                                 void* __restrict__ Cout,
                                                 ushort_t* __restrict__ vtout,
                                                 int N, int K) {
  __shared__ ushort_t As[128 * 64];
  __shared__ ushort_t Bs[128 * 64];
  const int tid = threadIdx.x;
  const int wave = tid >> 6, lane = tid & 63;
  const int c = lane & 15, g = lane >> 4;
  const int wm = wave >> 1, wn = wave & 1;

  // bijective XCD swizzle (nwg % 8 == 0 for all our launches)
  const int nwg = gridDim.x * gridDim.y;
  int wg = blockIdx.y * gridDim.x + blockIdx.x;
  {
    const int qd = nwg >> 3, rm = nwg & 7;
    const int xcd = wg & 7, idx = wg >> 3;
    wg = (xcd < rm ? xcd * (qd + 1) : rm * (qd + 1) + (xcd - rm) * qd) + idx;
  }
  const int bx = wg % gridDim.x, by = wg / gridDim.x;

  f32x4 acc[4][4];
#pragma unroll
  for (int m = 0; m < 4; m++)
#pragma unroll
    for (int n = 0; n < 4; n++) acc[m][n] = (f32x4){0.f, 0.f, 0.f, 0.f};

  for (int k0 = 0; k0 < K; k0 += 64) {
#pragma unroll
    for (int i = 0; i < 4; i++) {
      const int flat = i * 256 + tid;
      const ushort_t* srcA = A + (size_t)(by * 128 + (flat >> 3)) * K + k0 + (flat & 7) * 8;
      const ushort_t* srcB = Bt + (size_t)(bx * 128 + (flat >> 3)) * K + k0 + (flat & 7) * 8;
      const int ldsoff = (i * 256 + wave * 64) * 16;
      __builtin_amdgcn_global_load_lds((const AS1 void*)srcA,
                                       (AS3 void*)((char*)As + ldsoff), 16, 0, 0);
      __builtin_amdgcn_global_load_lds((const AS1 void*)srcB,
                                       (AS3 void*)((char*)Bs + ldsoff), 16, 0, 0);
    }
    __syncthreads();
#pragma unroll
    for (int kk = 0; kk < 2; kk++) {
      short8 af[4], bfr[4];
#pragma unroll
      for (int m = 0; m < 4; m++)
        af[m] = *(const short8*)(As + (wm * 64 + m * 16 + c) * 64 + kk * 32 + g * 8);
#pragma unroll
      for (int n = 0; n < 4; n++)
        bfr[n] = *(const short8*)(Bs + (wn * 64 + n * 16 + c) * 64 + kk * 32 + g * 8);
#pragma unroll
      for (int m = 0; m < 4; m++)
#pragma unroll
        for (int n = 0; n < 4; n++)
          acc[m][n] = __builtin_amdgcn_mfma_f32_16x16x32_bf16(af[m], bfr[n], acc[m][n], 0, 0, 0);
    }
    __syncthreads();
  }

  if (OUTMODE == 2 && bx >= 16) {
    // V columns: write transposed into Vt[b][h][d][t]; acc rows r=0..3 are
    // consecutive t -> contiguous short4 store.
#pragma unroll
    for (int m = 0; m < 4; m++)
#pragma unroll
      for (int n = 0; n < 4; n++) {
        const int cv = bx * 128 + wn * 64 + n * 16 + c - 2048;  // 0..1023
        const int hh = cv >> 6, d = cv & 63;
        const int row = by * 128 + wm * 64 + m * 16 + g * 4;
        const int bb = row >> 11, t = row & 2047;
        short4 o;
        o.x = (short)f2bf(acc[m][n][0]);
        o.y = (short)f2bf(acc[m][n][1]);
        o.z = (short)f2bf(acc[m][n][2]);
        o.w = (short)f2bf(acc[m][n][3]);
        *(short4*)(vtout + ((size_t)((bb * 16 + hh) * 64 + d)) * 2048 + t) = o;
      }
    return;
  }

#pragma unroll
  for (int m = 0; m < 4; m++)
#pragma unroll
    for (int n = 0; n < 4; n++) {
      const int col = bx * 128 + wn * 64 + n * 16 + c;
#pragma unroll
      for (int r = 0; r < 4; r++) {
        const int row = by * 128 + wm * 64 + m * 16 + g * 4 + r;
        if (OUTMODE != 0)
          ((ushort_t*)Cout)[(size_t)row * N + col] = f2bf(acc[m][n][r]);
        else
          ((float*)Cout)[(size_t)row * N + col] = acc[m][n][r];
      }
    }
}

// ---------------- flash attention, causal, hs=64 ----------------------------
// Grid (16, H, B), 4 waves x 32 q-rows, 64-key tiles, 32x32x16 MFMA.
// S^T = K*Q^T: lane owns q = lane&31; hi = lane>>5 selects key sub-slice.
// Softmax: in-register tree + ONE shfl_xor(32). P -> PV B-fragment: cvt_pk
// pairs + half-exchange via shfl_xor(32) + cndmask. K/V LDS-staged
// (global_load_lds, XOR-swizzled), double-buffered. QK^T split into two
// independent 2-MFMA chains per half (ILP); setprio(1) around MFMA clusters.

// Stage one 64x64 bf16 tile pair into LDS. LDS row r (128B) holds global
// 16B-block u at slot u^(r&7); reads apply byte ^= ((r&7)<<4).
__device__ __forceinline__ void stage_kv(const ushort_t* __restrict__ Kp,
                                         const ushort_t* __restrict__ Vt,
                                         ushort_t* Kl, ushort_t* Vl,
                                         int kb, int wave, int lane) {
  const int C3 = 3072, T = 2048;
#pragma unroll
  for (int j = 0; j < 2; j++) {
    const int rbase = wave * 16 + j * 8;
    const int r = rbase + (lane >> 3);
    const int cbg = ((lane & 7) ^ (r & 7)) << 4;  // pre-swizzled global byte col
    const int ldsbase = rbase * 128;               // + lane*16 implicit
    __builtin_amdgcn_global_load_lds(
        (const AS1 void*)(Kp + (size_t)(kb + r) * C3 + (cbg >> 1)),
        (AS3 void*)((char*)Kl + ldsbase), 16, 0, 0);
    __builtin_amdgcn_global_load_lds(
        (const AS1 void*)(Vt + (size_t)r * T + kb + (cbg >> 1)),
        (AS3 void*)((char*)Vl + ldsbase), 16, 0, 0);
  }
}

__global__ __launch_bounds__(256, 2) void k_attn(const ushort_t* __restrict__ qkv,
                                                 const ushort_t* __restrict__ vt,
                                                 ushort_t* __restrict__ y) {
  const int T = 2048, C3 = 3072, Cc = 1024;
  __shared__ ushort_t Kl[2][64 * 64];
  __shared__ ushort_t Vl[2][64 * 64];

  const int tid = threadIdx.x;
  const int wave = tid >> 6, lane = tid & 63;
  const int l31 = lane & 31, hi = lane >> 5;
  const bool hib = (hi != 0);
  const int swr = (l31 & 7) << 4;  // LDS read swizzle for rows l31, 32+l31
  const int b = blockIdx.z, h = blockIdx.y;
  const int qi = 15 - blockIdx.x;  // heavy blocks first (LPT schedule)
  const int qbase = qi * 128 + wave * 32;
  const int q = qbase + l31;

  const size_t base = (size_t)b * T * C3 + h * 64;
  const ushort_t* Q = qkv + base;
  const ushort_t* Kp = qkv + base + 1024;
  const ushort_t* Vt = vt + (size_t)((b * 16 + h) * 64) * T;

  const float KS = 0.125f * 1.44269504f;  // 1/sqrt(64) * log2(e)
  const float THR = 8.0f;                 // defer-max threshold (exp2 units)

  // Q^T B-fragments: B[k=16i+8hi+r][q=l31] = Q[q][16i+8hi+r]
  short8 qfr[4];
  {
    const ushort_t* qp = Q + (size_t)q * C3 + 8 * hi;
#pragma unroll
    for (int i = 0; i < 4; i++) qfr[i] = *(const short8*)(qp + 16 * i);
  }

  f32x16 yacc0 = (f32x16)(0.0f), yacc1 = (f32x16)(0.0f);  // d-halves 0..31, 32..63
  float mx = -3.0e38f, ssum = 0.f;

  const int nk_blk = (qi + 1) * 128;  // block-uniform trip count
  stage_kv(Kp, Vt, Kl[0], Vl[0], 0, wave, lane);
  __syncthreads();
  int cur = 0;

  for (int kb = 0; kb < nk_blk; kb += 64) {
    if (kb + 64 < nk_blk)
      stage_kv(Kp, Vt, Kl[cur ^ 1], Vl[cur ^ 1], kb + 64, wave, lane);

    if (kb < qbase + 32) {  // wave-uniform: this wave has live rows in tile
      const char* Kbuf = (const char*)Kl[cur];
      const char* Vbuf = (const char*)Vl[cur];

      // ---- QK^T: S^T[key][q]; 2 key-sub-blocks x 2 partial chains (ILP) ----
      f32x16 s0 = (f32x16)(0.0f), s1 = (f32x16)(0.0f);
      {
        f32x16 s0b = (f32x16)(0.0f), s1b = (f32x16)(0.0f);
        short8 ka0[4], ka1[4];
#pragma unroll
        for (int i = 0; i < 4; i++) {
          const int colb = (32 * i + 16 * hi) ^ swr;
          ka0[i] = *(const short8*)(Kbuf + l31 * 128 + colb);
          ka1[i] = *(const short8*)(Kbuf + (32 + l31) * 128 + colb);
        }
        __builtin_amdgcn_s_setprio(1);
        s0 = __builtin_amdgcn_mfma_f32_32x32x16_bf16(ka0[0], qfr[0], s0, 0, 0, 0);
        s1 = __builtin_amdgcn_mfma_f32_32x32x16_bf16(ka1[0], qfr[0], s1, 0, 0, 0);
        s0b = __builtin_amdgcn_mfma_f32_32x32x16_bf16(ka0[2], qfr[2], s0b, 0, 0, 0);
        s1b = __builtin_amdgcn_mfma_f32_32x32x16_bf16(ka1[2], qfr[2], s1b, 0, 0, 0);
        s0 = __builtin_amdgcn_mfma_f32_32x32x16_bf16(ka0[1], qfr[1], s0, 0, 0, 0);
        s1 = __builtin_amdgcn_mfma_f32_32x32x16_bf16(ka1[1], qfr[1], s1, 0, 0, 0);
        s0b = __builtin_amdgcn_mfma_f32_32x32x16_bf16(ka0[3], qfr[3], s0b, 0, 0, 0);
        s1b = __builtin_amdgcn_mfma_f32_32x32x16_bf16(ka1[3], qfr[3], s1b, 0, 0, 0);
        __builtin_amdgcn_s_setprio(0);
        s0 += s0b;
        s1 += s1b;
      }

      // ---- causal mask (raw scores; key = kb + sub*32 + (r&3)+8*(r>>2)+4hi) ----
      if (kb + 63 > qbase) {
#pragma unroll
        for (int r = 0; r < 16; r++) {
          const int key = kb + (r & 3) + 8 * (r >> 2) + 4 * hi;
          if (key > q) s0[r] = -1.0e30f;
          if (key + 32 > q) s1[r] = -1.0e30f;
        }
      }

      // ---- online softmax for q = l31 (one cross-half exchange) ----
      float t16[16];
#pragma unroll
      for (int r = 0; r < 16; r++) t16[r] = fmaxf(s0[r], s1[r]);
#pragma unroll
      for (int r = 0; r < 8; r++) t16[r] = fmaxf(t16[r], t16[r + 8]);
#pragma unroll
      for (int r = 0; r < 4; r++) t16[r] = fmaxf(t16[r], t16[r + 4]);
      float tm = fmaxf(fmaxf(t16[0], t16[1]), fmaxf(t16[2], t16[3]));
      tm = fmaxf(tm, __shfl_xor(tm, 32));
      const float cand = tm * KS;

      if (__any(cand > mx + THR)) {  // defer-max rescale (T13)
        const float mnew = fmaxf(mx, cand);
        const float alpha = EXP2(mx - mnew);
        ssum *= alpha;
#pragma unroll
        for (int r = 0; r < 16; r++) { yacc0[r] *= alpha; yacc1[r] *= alpha; }
        mx = mnew;
      }

      // p overwrites s in place (VGPR relief)
#pragma unroll
      for (int r = 0; r < 16; r++) {
        s0[r] = EXP2(__builtin_fmaf(s0[r], KS, -mx));
        s1[r] = EXP2(__builtin_fmaf(s1[r], KS, -mx));
      }
      {
        float ss[16];
#pragma unroll
        for (int r = 0; r < 16; r++) ss[r] = s0[r] + s1[r];
#pragma unroll
        for (int r = 0; r < 8; r++) ss[r] += ss[r + 8];
#pragma unroll
        for (int r = 0; r < 4; r++) ss[r] += ss[r + 4];
        float ts = (ss[0] + ss[1]) + (ss[2] + ss[3]);
        ts += __shfl_xor(ts, 32);
        ssum += ts;
      }

      // ---- P -> bf16 pairs, then half-exchange -> P^T B-fragments ----
      // hi=0 owns keys {0..3,8..11}+16j; hi=1 owns {4..7,12..15}+16j.
      // Needed frag: hi=0: [own d0,d1, partner d0,d1]; hi=1: [partner d2,d3,
      // own d2,d3]. snd = hib?d0:d2 (and d1/d3); rcv = shfl_xor(snd,32).
      union U4 { unsigned u[4]; short8 v; };
      U4 pb[4];
      {
        unsigned dw[4][4];
#pragma unroll
        for (int j = 0; j < 2; j++) {
          dw[j][0] = cvt_pk_bf16(s0[j * 8 + 0], s0[j * 8 + 1]);
          dw[j][1] = cvt_pk_bf16(s0[j * 8 + 2], s0[j * 8 + 3]);
          dw[j][2] = cvt_pk_bf16(s0[j * 8 + 4], s0[j * 8 + 5]);
          dw[j][3] = cvt_pk_bf16(s0[j * 8 + 6], s0[j * 8 + 7]);
          dw[2 + j][0] = cvt_pk_bf16(s1[j * 8 + 0], s1[j * 8 + 1]);
          dw[2 + j][1] = cvt_pk_bf16(s1[j * 8 + 2], s1[j * 8 + 3]);
          dw[2 + j][2] = cvt_pk_bf16(s1[j * 8 + 4], s1[j * 8 + 5]);
          dw[2 + j][3] = cvt_pk_bf16(s1[j * 8 + 6], s1[j * 8 + 7]);
        }
#pragma unroll
        for (int j = 0; j < 4; j++) {
          const unsigned d0 = dw[j][0], d1 = dw[j][1], d2 = dw[j][2], d3 = dw[j][3];
          const unsigned snd0 = hib ? d0 : d2;
          const unsigned snd1 = hib ? d1 : d3;
          const unsigned rcv0 = (unsigned)__shfl_xor((int)snd0, 32);
          const unsigned rcv1 = (unsigned)__shfl_xor((int)snd1, 32);
          pb[j].u[0] = hib ? rcv0 : d0;
          pb[j].u[1] = hib ? rcv1 : d1;
          pb[j].u[2] = hib ? d2 : rcv0;
          pb[j].u[3] = hib ? d3 : rcv1;
        }
      }

      // ---- PV: y^T[d][q] += V^T[d][k] * P^T[k][q], k-chunks of 16 keys ----
      {
        short8 va0[4], va1[4];
#pragma unroll
        for (int sj = 0; sj < 4; sj++) {
          const int colb = (sj * 32 + 16 * hi) ^ swr;
          va0[sj] = *(const short8*)(Vbuf + l31 * 128 + colb);
          va1[sj] = *(const short8*)(Vbuf + (32 + l31) * 128 + colb);
        }
        __builtin_amdgcn_s_setprio(1);
#pragma unroll
        for (int sj = 0; sj < 4; sj++) {
          yacc0 = __builtin_amdgcn_mfma_f32_32x32x16_bf16(va0[sj], pb[sj].v, yacc0, 0, 0, 0);
          yacc1 = __builtin_amdgcn_mfma_f32_32x32x16_bf16(va1[sj], pb[sj].v, yacc1, 0, 0, 0);
        }
        __builtin_amdgcn_s_setprio(0);
      }
    }

    __syncthreads();  // drains vmcnt: next tile staged, this tile's reads done
    cur ^= 1;
  }

  // ---- normalize + store: d = dh*32 + (r&3)+8*(r>>2)+4hi, q = l31 ----
  const float inv = 1.0f / ssum;
  ushort_t* yp = y + (size_t)(b * T + q) * Cc + h * 64;
#pragma unroll
  for (int gi = 0; gi < 4; gi++) {
    short4 o0, o1;
    o0.x = (short)f2bf(yacc0[gi * 4 + 0] * inv);
    o0.y = (short)f2bf(yacc0[gi * 4 + 1] * inv);
    o0.z = (short)f2bf(yacc0[gi * 4 + 2] * inv);
    o0.w = (short)f2bf(yacc0[gi * 4 + 3] * inv);
    o1.x = (short)f2bf(yacc1[gi * 4 + 0] * inv);
    o1.y = (short)f2bf(yacc1[gi * 4 + 1] * inv);
    o1.z = (short)f2bf(yacc1[gi * 4 + 2] * inv);
    o1.w = (short)f2bf(yacc1[gi * 4 + 3] * inv);
    *(short4*)(yp + 8 * gi + 4 * hi) = o0;
    *(short4*)(yp + 32 + 8 * gi + 4 * hi) = o1;
  }
}

// ---------------------------------------------------------------------------
extern "C" void kernel_launch(void* const* d_in, const int* in_sizes, int n_in,
                              void* d_out, int out_size, void* d_ws, size_t ws_size,
                              hipStream_t stream) {
  const float* x = (const float*)d_in[0];     // (4, 2048, 1024)
  const float* Wat = (const float*)d_in[1];   // (1024, 3072)
  const float* Wpr = (const float*)d_in[2];   // (1024, 1024)
  float* out = (float*)d_out;                 // (4, 2048, 1024)

  const int T = 2048, B = 4, H = 16, Cc = 1024;
  const int M = B * T;  // 8192

  char* ws = (char*)d_ws;
  const size_t MB = 1024 * 1024;
  ushort_t* xb = (ushort_t*)ws;                 // 16 MB (x_bf16, then Vt)
  ushort_t* wat = (ushort_t*)(ws + 16 * MB);    // 6 MB
  ushort_t* wpt = (ushort_t*)(ws + 24 * MB);    // 2 MB
  ushort_t* qkv = (ushort_t*)(ws + 32 * MB);    // 48 MB
  ushort_t* yb = (ushort_t*)(ws + 80 * MB);     // 16 MB
  ushort_t* vtb = (ushort_t*)(ws + 48 * MB);    // 16 MB (inside qkv V-region, unused by Q/K)

  // NOTE: vtb must not alias GEMM1 inputs (xb is GEMM1's A!). Place Vt in the
  // qkv V-column region [48M,64M): GEMM1 writes Q/K cols to [32M,48M) rows
  // interleaved... qkv rows are 3072-wide so Q/K/V interleave per row — use a
  // separate region instead: yb area is free during GEMM1? No — keep it
  // simple and safe: Vt lives at [48M..64M) ONLY if qkv V-cols unused.
  // qkv is row-major 8192x3072: V columns are scattered through the whole
  // 48MB, NOT a contiguous sub-range. So place Vt in the former k_vt target:
  // xb region is GEMM1's A input — cannot overwrite during GEMM1!
  // Safe home: [80M,96M) is yb (attn output, written after GEMM1). Vt is
  // consumed by k_attn which also writes yb — overlap would corrupt.
  // ws_size >= 96MB per original layout; check for 112MB headroom:
  if (ws_size >= (size_t)112 * MB) {
    vtb = (ushort_t*)(ws + 96 * MB);
  } else {
    // Fallback: reuse wat+wpt region? Too small (16MB needed, 16MB available
    // at [16M,32M) total). Use [16M,32M): weights are dead after GEMMs start?
    // wat is GEMM1's B input — dead only after GEMM1. GEMM1 writes Vt during
    // its epilogue while wat is still live as its own input — but epilogue
    // writes happen after all K-loop reads of THIS block; other blocks may
    // still be reading wat. UNSAFE. Final choice: pack Vt into [48M,64M)?
    // unsafe as shown. Use yb region [80M,96M) for Vt and move y to
    // [16M,32M) (weights dead before k_attn runs: all GEMM1 blocks complete
    // before k_attn launches; GEMM2's B (wpt) at [24M,26M) would be
    // overwritten by y!). Move wpt load target to [64M,66M) instead.
    vtb = (ushort_t*)(ws + 80 * MB);
  }

  ushort_t* ybuf;
  ushort_t* wptbuf;
  if (ws_size >= (size_t)112 * MB) {
    ybuf = yb;                                  // [80M,96M)
    wptbuf = wpt;                               // [24M,26M)
  } else {
    ybuf = (ushort_t*)(ws + 16 * MB);           // [16M,32M) (wat dead post-GEMM1)
    wptbuf = (ushort_t*)(ws + 64 * MB);         // [64M,66M) (never aliases)
  }

  // 1. convert inputs to bf16 (weights transposed to [N][K])
  k_f32_to_bf16<<<dim3((M * Cc) / (8 * 256)), 256, 0, stream>>>(x, xb);
  k_transpose_bf16<<<dim3(3072 / 32, 1024 / 32), 256, 0, stream>>>(Wat, wat, 1024, 3072);
  k_transpose_bf16<<<dim3(1024 / 32, 1024 / 32), 256, 0, stream>>>(Wpr, wptbuf, 1024, 1024);

  // 2. qkv = x @ W_attn (Q,K cols -> qkv; V cols -> Vt transposed)
  k_gemm_bt<2><<<dim3(3072 / 128, M / 128), 256, 0, stream>>>(xb, wat, qkv, vtb, 3072, 1024);

  // 3. causal flash attention -> y (8192 x 1024 bf16)
  k_attn<<<dim3(16, H, B), 256, 0, stream>>>(qkv, vtb, ybuf);

  // 4. out = y @ W_proj   (8192 x 1024, fp32)
  k_gemm_bt<0><<<dim3(1024 / 128, M / 128), 256, 0, stream>>>(ybuf, wptbuf, out, nullptr, 1024, 1024);
}

// Round 12
// 196.317 us; speedup vs baseline: 1.2442x; 1.2442x over previous
//
#include <hip/hip_runtime.h>
#include <hip/hip_bf16.h>
#include <cstdint>
#include <cstddef>

// CausalSelfAttention: B=4, T=2048, C=1024, H=16, hs=64 (fp32 in/out, bf16 MFMA compute)
//
// Pipeline: x->bf16 | W^T bf16 | GEMM1 (qkv; V written transposed in epilogue)
//           | flash attn (32x32 MFMA, swapped operands) | GEMM2
//
// Workspace (needs 112 MiB; proven available in R11):
//   [0,16M)    x_bf16 (GEMM1 A)
//   [16M,22M)  W_attn^T bf16
//   [24M,26M)  W_proj^T bf16
//   [32M,80M)  qkv bf16 (8192 x 3072; V-cols unwritten in fused mode)
//   [80M,96M)  y bf16
//   [96M,112M) Vt[b][h][64][2048] bf16

typedef unsigned short ushort_t;
typedef __attribute__((ext_vector_type(8))) short short8;
typedef __attribute__((ext_vector_type(4))) float f32x4;
typedef __attribute__((ext_vector_type(16))) float f32x16;

#define AS1 __attribute__((address_space(1)))
#define AS3 __attribute__((address_space(3)))

#if __has_builtin(__builtin_amdgcn_exp2f)
#define EXP2(x) __builtin_amdgcn_exp2f(x)
#else
#define EXP2(x) exp2f(x)
#endif

__device__ __forceinline__ ushort_t f2bf(float f) {
  union { float f; unsigned u; } c; c.f = f;
  unsigned u = c.u;
  return (ushort_t)((u + 0x7FFFu + ((u >> 16) & 1u)) >> 16);  // RNE
}

// v_cvt_pk_bf16_f32: lo16 = bf16(a), hi16 = bf16(b)
__device__ __forceinline__ unsigned cvt_pk_bf16(float a, float b) {
  unsigned r;
  asm("v_cvt_pk_bf16_f32 %0, %1, %2" : "=v"(r) : "v"(a), "v"(b));
  return r;
}

// ---------------- fp32 -> bf16 elementwise (8 elems/thread) ----------------
__global__ __launch_bounds__(256) void k_f32_to_bf16(const float* __restrict__ in,
                                                     ushort_t* __restrict__ out) {
  const size_t i = ((size_t)blockIdx.x * 256 + threadIdx.x) * 8;
  f32x4 a = *(const f32x4*)(in + i);
  f32x4 b = *(const f32x4*)(in + i + 4);
  short8 o;
  o[0] = (short)f2bf(a[0]); o[1] = (short)f2bf(a[1]);
  o[2] = (short)f2bf(a[2]); o[3] = (short)f2bf(a[3]);
  o[4] = (short)f2bf(b[0]); o[5] = (short)f2bf(b[1]);
  o[6] = (short)f2bf(b[2]); o[7] = (short)f2bf(b[3]);
  *(short8*)(out + i) = o;
}

// ------------- fp32 (R x C) -> bf16 transposed (C x R), LDS-tiled ----------
__global__ __launch_bounds__(256) void k_transpose_bf16(const float* __restrict__ in,
                                                        ushort_t* __restrict__ out,
                                                        int R, int C) {
  __shared__ float tile[32][33];
  const int tx = threadIdx.x & 31, ty = threadIdx.x >> 5;  // 32x8
  const int c0 = blockIdx.x * 32, r0 = blockIdx.y * 32;
#pragma unroll
  for (int i = 0; i < 32; i += 8)
    tile[ty + i][tx] = in[(size_t)(r0 + ty + i) * C + c0 + tx];
  __syncthreads();
#pragma unroll
  for (int i = 0; i < 32; i += 8)
    out[(size_t)(c0 + ty + i) * R + r0 + tx] = f2bf(tile[tx][ty + i]);
}

// ---- V transpose (fallback only): qkv V-section -> Vt[b][h][d][t] ----
__global__ __launch_bounds__(256) void k_vt(const ushort_t* __restrict__ qkv,
                                            ushort_t* __restrict__ vt) {
  __shared__ ushort_t tl[64][72];
  const int T = 2048, C3 = 3072;
  const int t0 = blockIdx.x * 64, h = blockIdx.y, b = blockIdx.z;
  const int r = threadIdx.x >> 4;
  const int c4 = (threadIdx.x & 15) * 4;
  const ushort_t* src = qkv + (size_t)(b * T + t0) * C3 + 2048 + h * 64;
#pragma unroll
  for (int p = 0; p < 4; p++) {
    const int row = p * 16 + r;
    *(short4*)&tl[row][c4] = *(const short4*)(src + (size_t)row * C3 + c4);
  }
  __syncthreads();
  ushort_t* dst = vt + (size_t)((b * 16 + h) * 64) * T + t0;
#pragma unroll
  for (int p = 0; p < 4; p++) {
    const int d = p * 16 + r;
    short4 o;
    o.x = (short)tl[c4 + 0][d];
    o.y = (short)tl[c4 + 1][d];
    o.z = (short)tl[c4 + 2][d];
    o.w = (short)tl[c4 + 3][d];
    *(short4*)(dst + (size_t)d * T + c4) = o;
  }
}

// ---------------- bf16 GEMM: C[M,N] = A[M,K] * Bt[N,K]^T -------------------
// OUTMODE: 0 = fp32 out; 1 = bf16 out; 2 = bf16 out for cols<2048 plus
// V-transpose epilogue (cols>=2048 written as Vt[b][h][d][t]).
// XCD-aware bijective block swizzle (T1/m204): contiguous grid chunks per XCD
// so same-by neighbors (sharing the A-panel) hit the same L2.
template <int OUTMODE>
__global__ __launch_bounds__(256) void k_gemm_bt(const ushort_t* __restrict__ A,
                                                 const ushort_t* __restrict__ Bt,
                                                 void* __restrict__ Cout,
                                                 ushort_t* __restrict__ vtout,
                                                 int N, int K) {
  __shared__ ushort_t As[128 * 64];
  __shared__ ushort_t Bs[128 * 64];
  const int tid = threadIdx.x;
  const int wave = tid >> 6, lane = tid & 63;
  const int c = lane & 15, g = lane >> 4;
  const int wm = wave >> 1, wn = wave & 1;

  // bijective XCD swizzle (nwg % 8 == 0 for all our launches)
  const int nwg = gridDim.x * gridDim.y;
  int wg = blockIdx.y * gridDim.x + blockIdx.x;
  {
    const int qd = nwg >> 3, rm = nwg & 7;
    const int xcd = wg & 7, idx = wg >> 3;
    wg = (xcd < rm ? xcd * (qd + 1) : rm * (qd + 1) + (xcd - rm) * qd) + idx;
  }
  const int bx = wg % gridDim.x, by = wg / gridDim.x;

  f32x4 acc[4][4];
#pragma unroll
  for (int m = 0; m < 4; m++)
#pragma unroll
    for (int n = 0; n < 4; n++) acc[m][n] = (f32x4){0.f, 0.f, 0.f, 0.f};

  for (int k0 = 0; k0 < K; k0 += 64) {
#pragma unroll
    for (int i = 0; i < 4; i++) {
      const int flat = i * 256 + tid;
      const ushort_t* srcA = A + (size_t)(by * 128 + (flat >> 3)) * K + k0 + (flat & 7) * 8;
      const ushort_t* srcB = Bt + (size_t)(bx * 128 + (flat >> 3)) * K + k0 + (flat & 7) * 8;
      const int ldsoff = (i * 256 + wave * 64) * 16;
      __builtin_amdgcn_global_load_lds((const AS1 void*)srcA,
                                       (AS3 void*)((char*)As + ldsoff), 16, 0, 0);
      __builtin_amdgcn_global_load_lds((const AS1 void*)srcB,
                                       (AS3 void*)((char*)Bs + ldsoff), 16, 0, 0);
    }
    __syncthreads();
#pragma unroll
    for (int kk = 0; kk < 2; kk++) {
      short8 af[4], bfr[4];
#pragma unroll
      for (int m = 0; m < 4; m++)
        af[m] = *(const short8*)(As + (wm * 64 + m * 16 + c) * 64 + kk * 32 + g * 8);
#pragma unroll
      for (int n = 0; n < 4; n++)
        bfr[n] = *(const short8*)(Bs + (wn * 64 + n * 16 + c) * 64 + kk * 32 + g * 8);
#pragma unroll
      for (int m = 0; m < 4; m++)
#pragma unroll
        for (int n = 0; n < 4; n++)
          acc[m][n] = __builtin_amdgcn_mfma_f32_16x16x32_bf16(af[m], bfr[n], acc[m][n], 0, 0, 0);
    }
    __syncthreads();
  }

  if (OUTMODE == 2 && bx >= 16) {
    // V columns: write transposed into Vt[b][h][d][t]; acc rows r=0..3 are
    // consecutive t -> contiguous short4 store.
#pragma unroll
    for (int m = 0; m < 4; m++)
#pragma unroll
      for (int n = 0; n < 4; n++) {
        const int cv = bx * 128 + wn * 64 + n * 16 + c - 2048;  // 0..1023
        const int hh = cv >> 6, d = cv & 63;
        const int row = by * 128 + wm * 64 + m * 16 + g * 4;
        const int bb = row >> 11, t = row & 2047;
        short4 o;
        o.x = (short)f2bf(acc[m][n][0]);
        o.y = (short)f2bf(acc[m][n][1]);
        o.z = (short)f2bf(acc[m][n][2]);
        o.w = (short)f2bf(acc[m][n][3]);
        *(short4*)(vtout + ((size_t)((bb * 16 + hh) * 64 + d)) * 2048 + t) = o;
      }
    return;
  }

#pragma unroll
  for (int m = 0; m < 4; m++)
#pragma unroll
    for (int n = 0; n < 4; n++) {
      const int col = bx * 128 + wn * 64 + n * 16 + c;
#pragma unroll
      for (int r = 0; r < 4; r++) {
        const int row = by * 128 + wm * 64 + m * 16 + g * 4 + r;
        if (OUTMODE != 0)
          ((ushort_t*)Cout)[(size_t)row * N + col] = f2bf(acc[m][n][r]);
        else
          ((float*)Cout)[(size_t)row * N + col] = acc[m][n][r];
      }
    }
}

// ---------------- flash attention, causal, hs=64 ----------------------------
// Grid (16, H, B), 4 waves x 32 q-rows, 64-key tiles, 32x32x16 MFMA.
// S^T = K*Q^T: lane owns q = lane&31; hi = lane>>5 selects key sub-slice.
// Softmax: in-register tree + ONE shfl_xor(32). P -> PV B-fragment: cvt_pk
// pairs + half-exchange via shfl_xor(32)+cndmask. K/V LDS-staged, dbuf.
//
// qi mapping (R12): same-CU blocks under period-256 round-robin are
// {lin,lin+256,...} = same bx,h, different b. Choose qi so those 4 blocks'
// causal depths sum to a constant: t=(bx+(b>>1)*8)&15; qi=(b&1)?15-t:t.
// Per (h,b) it is a bijection on 0..15 (correctness-neutral); per CU
// sum(qi+1) = 34 for every bx -> balanced per-CU work.

// Stage one 64x64 bf16 tile pair into LDS. LDS row r (128B) holds global
// 16B-block u at slot u^(r&7); reads apply byte ^= ((r&7)<<4).
__device__ __forceinline__ void stage_kv(const ushort_t* __restrict__ Kp,
                                         const ushort_t* __restrict__ Vt,
                                         ushort_t* Kl, ushort_t* Vl,
                                         int kb, int wave, int lane) {
  const int C3 = 3072, T = 2048;
#pragma unroll
  for (int j = 0; j < 2; j++) {
    const int rbase = wave * 16 + j * 8;
    const int r = rbase + (lane >> 3);
    const int cbg = ((lane & 7) ^ (r & 7)) << 4;  // pre-swizzled global byte col
    const int ldsbase = rbase * 128;               // + lane*16 implicit
    __builtin_amdgcn_global_load_lds(
        (const AS1 void*)(Kp + (size_t)(kb + r) * C3 + (cbg >> 1)),
        (AS3 void*)((char*)Kl + ldsbase), 16, 0, 0);
    __builtin_amdgcn_global_load_lds(
        (const AS1 void*)(Vt + (size_t)r * T + kb + (cbg >> 1)),
        (AS3 void*)((char*)Vl + ldsbase), 16, 0, 0);
  }
}

__global__ __launch_bounds__(256, 2) void k_attn(const ushort_t* __restrict__ qkv,
                                                 const ushort_t* __restrict__ vt,
                                                 ushort_t* __restrict__ y) {
  const int T = 2048, C3 = 3072, Cc = 1024;
  __shared__ ushort_t Kl[2][64 * 64];
  __shared__ ushort_t Vl[2][64 * 64];

  const int tid = threadIdx.x;
  const int wave = tid >> 6, lane = tid & 63;
  const int l31 = lane & 31, hi = lane >> 5;
  const bool hib = (hi != 0);
  const int swr = (l31 & 7) << 4;  // LDS read swizzle for rows l31, 32+l31
  const int b = blockIdx.z, h = blockIdx.y;
  // complementary per-CU depth mapping (see header comment)
  const int tmap = ((int)blockIdx.x + ((b >> 1) << 3)) & 15;
  const int qi = (b & 1) ? (15 - tmap) : tmap;
  const int qbase = qi * 128 + wave * 32;
  const int q = qbase + l31;

  const size_t base = (size_t)b * T * C3 + h * 64;
  const ushort_t* Q = qkv + base;
  const ushort_t* Kp = qkv + base + 1024;
  const ushort_t* Vt = vt + (size_t)((b * 16 + h) * 64) * T;

  const float KS = 0.125f * 1.44269504f;  // 1/sqrt(64) * log2(e)
  const float THR = 8.0f;                 // defer-max threshold (exp2 units)

  // Q^T B-fragments: B[k=16i+8hi+r][q=l31] = Q[q][16i+8hi+r]
  short8 qfr[4];
  {
    const ushort_t* qp = Q + (size_t)q * C3 + 8 * hi;
#pragma unroll
    for (int i = 0; i < 4; i++) qfr[i] = *(const short8*)(qp + 16 * i);
  }

  f32x16 yacc0 = (f32x16)(0.0f), yacc1 = (f32x16)(0.0f);  // d-halves 0..31, 32..63
  float mx = -3.0e38f, ssum = 0.f;

  const int nk_blk = (qi + 1) * 128;  // block-uniform trip count
  stage_kv(Kp, Vt, Kl[0], Vl[0], 0, wave, lane);
  __syncthreads();
  int cur = 0;

  for (int kb = 0; kb < nk_blk; kb += 64) {
    if (kb + 64 < nk_blk)
      stage_kv(Kp, Vt, Kl[cur ^ 1], Vl[cur ^ 1], kb + 64, wave, lane);

    if (kb < qbase + 32) {  // wave-uniform: this wave has live rows in tile
      const char* Kbuf = (const char*)Kl[cur];
      const char* Vbuf = (const char*)Vl[cur];

      // ---- QK^T: S^T[key][q], two 32-key sub-blocks ----
      f32x16 s0 = (f32x16)(0.0f), s1 = (f32x16)(0.0f);
#pragma unroll
      for (int i = 0; i < 4; i++) {
        const int colb = (32 * i + 16 * hi) ^ swr;
        const short8 ka0 = *(const short8*)(Kbuf + l31 * 128 + colb);
        const short8 ka1 = *(const short8*)(Kbuf + (32 + l31) * 128 + colb);
        s0 = __builtin_amdgcn_mfma_f32_32x32x16_bf16(ka0, qfr[i], s0, 0, 0, 0);
        s1 = __builtin_amdgcn_mfma_f32_32x32x16_bf16(ka1, qfr[i], s1, 0, 0, 0);
      }

      // ---- causal mask (raw scores; key = kb + sub*32 + (r&3)+8*(r>>2)+4hi) ----
      if (kb + 63 > qbase) {
#pragma unroll
        for (int r = 0; r < 16; r++) {
          const int key = kb + (r & 3) + 8 * (r >> 2) + 4 * hi;
          if (key > q) s0[r] = -1.0e30f;
          if (key + 32 > q) s1[r] = -1.0e30f;
        }
      }

      // ---- online softmax for q = l31 (one cross-half exchange) ----
      float t16[16];
#pragma unroll
      for (int r = 0; r < 16; r++) t16[r] = fmaxf(s0[r], s1[r]);
#pragma unroll
      for (int r = 0; r < 8; r++) t16[r] = fmaxf(t16[r], t16[r + 8]);
#pragma unroll
      for (int r = 0; r < 4; r++) t16[r] = fmaxf(t16[r], t16[r + 4]);
      float tm = fmaxf(fmaxf(t16[0], t16[1]), fmaxf(t16[2], t16[3]));
      tm = fmaxf(tm, __shfl_xor(tm, 32));
      const float cand = tm * KS;

      if (__any(cand > mx + THR)) {  // defer-max rescale (T13)
        const float mnew = fmaxf(mx, cand);
        const float alpha = EXP2(mx - mnew);
        ssum *= alpha;
#pragma unroll
        for (int r = 0; r < 16; r++) { yacc0[r] *= alpha; yacc1[r] *= alpha; }
        mx = mnew;
      }

      // p overwrites s in place (VGPR relief)
#pragma unroll
      for (int r = 0; r < 16; r++) {
        s0[r] = EXP2(__builtin_fmaf(s0[r], KS, -mx));
        s1[r] = EXP2(__builtin_fmaf(s1[r], KS, -mx));
      }
      {
        float ss[16];
#pragma unroll
        for (int r = 0; r < 16; r++) ss[r] = s0[r] + s1[r];
#pragma unroll
        for (int r = 0; r < 8; r++) ss[r] += ss[r + 8];
#pragma unroll
        for (int r = 0; r < 4; r++) ss[r] += ss[r + 4];
        float ts = (ss[0] + ss[1]) + (ss[2] + ss[3]);
        ts += __shfl_xor(ts, 32);
        ssum += ts;
      }

      // ---- P -> bf16 pairs, then half-exchange -> P^T B-fragments ----
      // hi=0 owns keys {0..3,8..11}+16j; hi=1 owns {4..7,12..15}+16j.
      // Needed frag: hi=0: [own d0,d1, partner d0,d1]; hi=1: [partner d2,d3,
      // own d2,d3]. snd = hib?d0:d2 (and d1/d3); rcv = shfl_xor(snd,32).
      union U4 { unsigned u[4]; short8 v; };
      U4 pb[4];
      {
        unsigned dw[4][4];
#pragma unroll
        for (int j = 0; j < 2; j++) {
          dw[j][0] = cvt_pk_bf16(s0[j * 8 + 0], s0[j * 8 + 1]);
          dw[j][1] = cvt_pk_bf16(s0[j * 8 + 2], s0[j * 8 + 3]);
          dw[j][2] = cvt_pk_bf16(s0[j * 8 + 4], s0[j * 8 + 5]);
          dw[j][3] = cvt_pk_bf16(s0[j * 8 + 6], s0[j * 8 + 7]);
          dw[2 + j][0] = cvt_pk_bf16(s1[j * 8 + 0], s1[j * 8 + 1]);
          dw[2 + j][1] = cvt_pk_bf16(s1[j * 8 + 2], s1[j * 8 + 3]);
          dw[2 + j][2] = cvt_pk_bf16(s1[j * 8 + 4], s1[j * 8 + 5]);
          dw[2 + j][3] = cvt_pk_bf16(s1[j * 8 + 6], s1[j * 8 + 7]);
        }
#pragma unroll
        for (int j = 0; j < 4; j++) {
          const unsigned d0 = dw[j][0], d1 = dw[j][1], d2 = dw[j][2], d3 = dw[j][3];
          const unsigned snd0 = hib ? d0 : d2;
          const unsigned snd1 = hib ? d1 : d3;
          const unsigned rcv0 = (unsigned)__shfl_xor((int)snd0, 32);
          const unsigned rcv1 = (unsigned)__shfl_xor((int)snd1, 32);
          pb[j].u[0] = hib ? rcv0 : d0;
          pb[j].u[1] = hib ? rcv1 : d1;
          pb[j].u[2] = hib ? d2 : rcv0;
          pb[j].u[3] = hib ? d3 : rcv1;
        }
      }

      // ---- PV: y^T[d][q] += V^T[d][k] * P^T[k][q], k-chunks of 16 keys ----
#pragma unroll
      for (int sj = 0; sj < 4; sj++) {
        const int colb = (sj * 32 + 16 * hi) ^ swr;
        const short8 va0 = *(const short8*)(Vbuf + l31 * 128 + colb);
        const short8 va1 = *(const short8*)(Vbuf + (32 + l31) * 128 + colb);
        yacc0 = __builtin_amdgcn_mfma_f32_32x32x16_bf16(va0, pb[sj].v, yacc0, 0, 0, 0);
        yacc1 = __builtin_amdgcn_mfma_f32_32x32x16_bf16(va1, pb[sj].v, yacc1, 0, 0, 0);
      }
    }

    __syncthreads();  // drains vmcnt: next tile staged, this tile's reads done
    cur ^= 1;
  }

  // ---- normalize + store: d = dh*32 + (r&3)+8*(r>>2)+4hi, q = l31 ----
  const float inv = 1.0f / ssum;
  ushort_t* yp = y + (size_t)(b * T + q) * Cc + h * 64;
#pragma unroll
  for (int gi = 0; gi < 4; gi++) {
    short4 o0, o1;
    o0.x = (short)f2bf(yacc0[gi * 4 + 0] * inv);
    o0.y = (short)f2bf(yacc0[gi * 4 + 1] * inv);
    o0.z = (short)f2bf(yacc0[gi * 4 + 2] * inv);
    o0.w = (short)f2bf(yacc0[gi * 4 + 3] * inv);
    o1.x = (short)f2bf(yacc1[gi * 4 + 0] * inv);
    o1.y = (short)f2bf(yacc1[gi * 4 + 1] * inv);
    o1.z = (short)f2bf(yacc1[gi * 4 + 2] * inv);
    o1.w = (short)f2bf(yacc1[gi * 4 + 3] * inv);
    *(short4*)(yp + 8 * gi + 4 * hi) = o0;
    *(short4*)(yp + 32 + 8 * gi + 4 * hi) = o1;
  }
}

// ---------------------------------------------------------------------------
extern "C" void kernel_launch(void* const* d_in, const int* in_sizes, int n_in,
                              void* d_out, int out_size, void* d_ws, size_t ws_size,
                              hipStream_t stream) {
  const float* x = (const float*)d_in[0];     // (4, 2048, 1024)
  const float* Wat = (const float*)d_in[1];   // (1024, 3072)
  const float* Wpr = (const float*)d_in[2];   // (1024, 1024)
  float* out = (float*)d_out;                 // (4, 2048, 1024)

  const int T = 2048, B = 4, H = 16, Cc = 1024;
  const int M = B * T;  // 8192

  char* ws = (char*)d_ws;
  const size_t MB = 1024 * 1024;
  ushort_t* xb = (ushort_t*)ws;                 // 16 MB
  ushort_t* wat = (ushort_t*)(ws + 16 * MB);    // 6 MB
  ushort_t* wpt = (ushort_t*)(ws + 24 * MB);    // 2 MB
  ushort_t* qkv = (ushort_t*)(ws + 32 * MB);    // 48 MB
  ushort_t* yb = (ushort_t*)(ws + 80 * MB);     // 16 MB

  const bool big_ws = (ws_size >= (size_t)112 * MB);  // proven true in R11

  // 1. convert inputs to bf16 (weights transposed to [N][K])
  k_f32_to_bf16<<<dim3((M * Cc) / (8 * 256)), 256, 0, stream>>>(x, xb);
  k_transpose_bf16<<<dim3(3072 / 32, 1024 / 32), 256, 0, stream>>>(Wat, wat, 1024, 3072);
  k_transpose_bf16<<<dim3(1024 / 32, 1024 / 32), 256, 0, stream>>>(Wpr, wpt, 1024, 1024);

  if (big_ws) {
    ushort_t* vtb = (ushort_t*)(ws + 96 * MB);  // 16 MB
    // 2. qkv = x @ W_attn (Q,K cols -> qkv; V cols -> Vt transposed, fused)
    k_gemm_bt<2><<<dim3(3072 / 128, M / 128), 256, 0, stream>>>(xb, wat, qkv, vtb, 3072, 1024);
    // 3. causal flash attention -> y
    k_attn<<<dim3(16, H, B), 256, 0, stream>>>(qkv, vtb, yb);
  } else {
    // Fallback: plain GEMM1 + separate V-transpose (Vt reuses xb, dead after GEMM1)
    ushort_t* vtb = xb;
    k_gemm_bt<1><<<dim3(3072 / 128, M / 128), 256, 0, stream>>>(xb, wat, qkv, nullptr, 3072, 1024);
    k_vt<<<dim3(T / 64, H, B), 256, 0, stream>>>(qkv, vtb);
    k_attn<<<dim3(16, H, B), 256, 0, stream>>>(qkv, vtb, yb);
  }

  // 4. out = y @ W_proj   (8192 x 1024, fp32)
  k_gemm_bt<0><<<dim3(1024 / 128, M / 128), 256, 0, stream>>>(yb, wpt, out, nullptr, 1024, 1024);
}

// Round 13
// 182.546 us; speedup vs baseline: 1.3381x; 1.0754x over previous
//
#include <hip/hip_runtime.h>
#include <hip/hip_bf16.h>
#include <cstdint>
#include <cstddef>

// CausalSelfAttention: B=4, T=2048, C=1024, H=16, hs=64 (fp32 in/out, bf16 MFMA compute)
//
// Pipeline: x->bf16 | W^T bf16 | GEMM1 (qkv; V written transposed in epilogue)
//           | flash attn (32x32 MFMA, swapped operands) | GEMM2
//
// GEMM = 3-deep counted-vmcnt pipeline (T3+T4) + XOR-swizzled LDS (T2) +
// setprio (T5): BM=256 BN=128 BK=64, 8 waves, 144KB LDS, stages issued 2
// K-tiles ahead, boundary wait vmcnt(6) (prefetch never drains).
//
// Workspace (needs 112 MiB; proven available in R11):
//   [0,16M)    x_bf16 | [16M,22M) W_attn^T | [24M,26M) W_proj^T
//   [32M,80M)  qkv bf16 | [80M,96M) y bf16 | [96M,112M) Vt[b][h][64][2048]

typedef unsigned short ushort_t;
typedef __attribute__((ext_vector_type(8))) short short8;
typedef __attribute__((ext_vector_type(4))) float f32x4;
typedef __attribute__((ext_vector_type(16))) float f32x16;

#define AS1 __attribute__((address_space(1)))
#define AS3 __attribute__((address_space(3)))

#if __has_builtin(__builtin_amdgcn_exp2f)
#define EXP2(x) __builtin_amdgcn_exp2f(x)
#else
#define EXP2(x) exp2f(x)
#endif

__device__ __forceinline__ ushort_t f2bf(float f) {
  union { float f; unsigned u; } c; c.f = f;
  unsigned u = c.u;
  return (ushort_t)((u + 0x7FFFu + ((u >> 16) & 1u)) >> 16);  // RNE
}

__device__ __forceinline__ unsigned cvt_pk_bf16(float a, float b) {
  unsigned r;
  asm("v_cvt_pk_bf16_f32 %0, %1, %2" : "=v"(r) : "v"(a), "v"(b));
  return r;
}

// ---------------- fp32 -> bf16 elementwise (8 elems/thread) ----------------
__global__ __launch_bounds__(256) void k_f32_to_bf16(const float* __restrict__ in,
                                                     ushort_t* __restrict__ out) {
  const size_t i = ((size_t)blockIdx.x * 256 + threadIdx.x) * 8;
  f32x4 a = *(const f32x4*)(in + i);
  f32x4 b = *(const f32x4*)(in + i + 4);
  short8 o;
  o[0] = (short)f2bf(a[0]); o[1] = (short)f2bf(a[1]);
  o[2] = (short)f2bf(a[2]); o[3] = (short)f2bf(a[3]);
  o[4] = (short)f2bf(b[0]); o[5] = (short)f2bf(b[1]);
  o[6] = (short)f2bf(b[2]); o[7] = (short)f2bf(b[3]);
  *(short8*)(out + i) = o;
}

// ------------- fp32 (R x C) -> bf16 transposed (C x R), LDS-tiled ----------
__global__ __launch_bounds__(256) void k_transpose_bf16(const float* __restrict__ in,
                                                        ushort_t* __restrict__ out,
                                                        int R, int C) {
  __shared__ float tile[32][33];
  const int tx = threadIdx.x & 31, ty = threadIdx.x >> 5;  // 32x8
  const int c0 = blockIdx.x * 32, r0 = blockIdx.y * 32;
#pragma unroll
  for (int i = 0; i < 32; i += 8)
    tile[ty + i][tx] = in[(size_t)(r0 + ty + i) * C + c0 + tx];
  __syncthreads();
#pragma unroll
  for (int i = 0; i < 32; i += 8)
    out[(size_t)(c0 + ty + i) * R + r0 + tx] = f2bf(tile[tx][ty + i]);
}

// ---- V transpose (fallback only): qkv V-section -> Vt[b][h][d][t] ----
__global__ __launch_bounds__(256) void k_vt(const ushort_t* __restrict__ qkv,
                                            ushort_t* __restrict__ vt) {
  __shared__ ushort_t tl[64][72];
  const int T = 2048, C3 = 3072;
  const int t0 = blockIdx.x * 64, h = blockIdx.y, b = blockIdx.z;
  const int r = threadIdx.x >> 4;
  const int c4 = (threadIdx.x & 15) * 4;
  const ushort_t* src = qkv + (size_t)(b * T + t0) * C3 + 2048 + h * 64;
#pragma unroll
  for (int p = 0; p < 4; p++) {
    const int row = p * 16 + r;
    *(short4*)&tl[row][c4] = *(const short4*)(src + (size_t)row * C3 + c4);
  }
  __syncthreads();
  ushort_t* dst = vt + (size_t)((b * 16 + h) * 64) * T + t0;
#pragma unroll
  for (int p = 0; p < 4; p++) {
    const int d = p * 16 + r;
    short4 o;
    o.x = (short)tl[c4 + 0][d];
    o.y = (short)tl[c4 + 1][d];
    o.z = (short)tl[c4 + 2][d];
    o.w = (short)tl[c4 + 3][d];
    *(short4*)(dst + (size_t)d * T + c4) = o;
  }
}

// ---- stage one 128x64 bf16 unit: global (row-stride K) -> LDS, swizzled ----
// LDS row r holds global 16B-block u at slot u^(r&7); reads XOR ((r&7)<<4).
__device__ __forceinline__ void stage_unit(const ushort_t* __restrict__ X, int K,
                                           char* ldsbase, int tid, int w) {
#pragma unroll
  for (int j = 0; j < 2; j++) {
    const int rl = j * 64 + (tid >> 3);
    const int gc = ((tid & 7) ^ (rl & 7)) << 3;  // pre-swizzled col (elems)
    __builtin_amdgcn_global_load_lds(
        (const AS1 void*)(X + (size_t)rl * K + gc),
        (AS3 void*)(ldsbase + (j * 64 + w * 8) * 128), 16, 0, 0);
  }
}

// ---------------- bf16 GEMM: C[M,N] = A[M,K] * Bt[N,K]^T -------------------
// BM=256, BN=128, BK=64; 512 threads = 8 waves (4M x 2N), per-wave 64x64 out.
// 3 LDS buffers (144KB): compute tile t from buf[t%3] while tile t+2 stages
// into buf[(t+2)%3]; boundary s_waitcnt vmcnt(6) keeps t+2's 6 loads in
// flight (counted, never drains). Raw s_barrier (no implicit drain).
// OUTMODE: 0 = fp32 C; 1 = bf16 C; 2 = bf16 C for cols<2048 + fused
// V-transpose (cols>=2048 -> Vt[b][h][d][t]).
template <int OUTMODE>
__global__ __launch_bounds__(512, 2) void k_gemm256(const ushort_t* __restrict__ A,
                                                    const ushort_t* __restrict__ Bt,
                                                    void* __restrict__ Cout,
                                                    ushort_t* __restrict__ vtout,
                                                    int N, int K) {
  __shared__ ushort_t As[3 * 256 * 64];  // 96KB: 3 bufs x [256][64]
  __shared__ ushort_t Bs[3 * 128 * 64];  // 48KB: 3 bufs x [128][64]

  const int tid = threadIdx.x;
  const int w = tid >> 6, lane = tid & 63;
  const int c = lane & 15, g = lane >> 4;
  const int wr = w >> 1, wc = w & 1;

  // bijective XCD swizzle (nwg % 8 == 0 for all our launches)
  const int nwg = gridDim.x * gridDim.y;
  int wg = blockIdx.y * gridDim.x + blockIdx.x;
  {
    const int qd = nwg >> 3, rm = nwg & 7;
    const int xcd = wg & 7, idx = wg >> 3;
    wg = (xcd < rm ? xcd * (qd + 1) : rm * (qd + 1) + (xcd - rm) * qd) + idx;
  }
  const int bxn = wg % gridDim.x, by = wg / gridDim.x;

  const ushort_t* Abase = A + (size_t)(by * 256) * K;
  const ushort_t* Bbase = Bt + (size_t)(bxn * 128) * K;
  const int NT = K >> 6;  // K-tiles (16 for K=1024)

  auto stageT = [&](int tt) {
    const int s = tt % 3, k0 = tt * 64;
    char* Ab = (char*)As + s * 32768;
    char* Bb = (char*)Bs + s * 16384;
    stage_unit(Abase + k0, K, Ab, tid, w);
    stage_unit(Abase + (size_t)128 * K + k0, K, Ab + 16384, tid, w);
    stage_unit(Bbase + k0, K, Bb, tid, w);
  };

  f32x4 acc[4][4];
#pragma unroll
  for (int m = 0; m < 4; m++)
#pragma unroll
    for (int n = 0; n < 4; n++) acc[m][n] = (f32x4){0.f, 0.f, 0.f, 0.f};

  // prologue: stage tiles 0,1; wait tile 0 (tile 1's 6 loads stay in flight)
  stageT(0);
  stageT(1);
  __builtin_amdgcn_sched_barrier(0);
  asm volatile("s_waitcnt vmcnt(6)" ::: "memory");
  __builtin_amdgcn_s_barrier();
  __builtin_amdgcn_sched_barrier(0);

  for (int t = 0; t < NT; ++t) {
    const int cur = t % 3;
    const char* Ab = (const char*)As + cur * 32768;
    const char* Bb = (const char*)Bs + cur * 16384;

    // ---- phase 0 (kk = 0) ----
    {
      short8 af[4], bv[4];
#pragma unroll
      for (int m = 0; m < 4; m++) {
        const int r = wr * 64 + m * 16 + c;
        af[m] = *(const short8*)(Ab + r * 128 + ((g * 16) ^ ((r & 7) << 4)));
      }
#pragma unroll
      for (int n = 0; n < 4; n++) {
        const int r = wc * 64 + n * 16 + c;
        bv[n] = *(const short8*)(Bb + r * 128 + ((g * 16) ^ ((r & 7) << 4)));
      }
      if (t + 2 < NT) stageT(t + 2);  // into buf[(t+2)%3]: free since t-1 ended
      __builtin_amdgcn_s_barrier();
      __builtin_amdgcn_s_setprio(1);
#pragma unroll
      for (int m = 0; m < 4; m++)
#pragma unroll
        for (int n = 0; n < 4; n++)
          acc[m][n] = __builtin_amdgcn_mfma_f32_16x16x32_bf16(af[m], bv[n], acc[m][n], 0, 0, 0);
      __builtin_amdgcn_s_setprio(0);
      __builtin_amdgcn_s_barrier();
    }

    // ---- phase 1 (kk = 1) ----
    {
      short8 af[4], bv[4];
#pragma unroll
      for (int m = 0; m < 4; m++) {
        const int r = wr * 64 + m * 16 + c;
        af[m] = *(const short8*)(Ab + r * 128 + ((64 + g * 16) ^ ((r & 7) << 4)));
      }
#pragma unroll
      for (int n = 0; n < 4; n++) {
        const int r = wc * 64 + n * 16 + c;
        bv[n] = *(const short8*)(Bb + r * 128 + ((64 + g * 16) ^ ((r & 7) << 4)));
      }
      __builtin_amdgcn_s_barrier();
      __builtin_amdgcn_s_setprio(1);
#pragma unroll
      for (int m = 0; m < 4; m++)
#pragma unroll
        for (int n = 0; n < 4; n++)
          acc[m][n] = __builtin_amdgcn_mfma_f32_16x16x32_bf16(af[m], bv[n], acc[m][n], 0, 0, 0);
      __builtin_amdgcn_s_setprio(0);
    }

    // ---- tile boundary: ensure tile t+1 fully staged for ALL waves ----
    if (t + 1 < NT) {
      __builtin_amdgcn_sched_barrier(0);
      if (t + 2 < NT)
        asm volatile("s_waitcnt vmcnt(6)" ::: "memory");  // t+2's stay in flight
      else
        asm volatile("s_waitcnt vmcnt(0)" ::: "memory");  // last tile: drain once
      __builtin_amdgcn_s_barrier();
      __builtin_amdgcn_sched_barrier(0);
    }
  }

  // ---- epilogue ----
  if (OUTMODE == 2 && bxn >= 16) {
    // V columns -> Vt[b][h][d][t]; acc regs r=0..3 are consecutive t.
#pragma unroll
    for (int m = 0; m < 4; m++)
#pragma unroll
      for (int n = 0; n < 4; n++) {
        const int cv = bxn * 128 + wc * 64 + n * 16 + c - 2048;  // 0..1023
        const int hh = cv >> 6, d = cv & 63;
        const int row = by * 256 + wr * 64 + m * 16 + g * 4;
        const int bb = row >> 11, tt = row & 2047;
        short4 o;
        o.x = (short)f2bf(acc[m][n][0]);
        o.y = (short)f2bf(acc[m][n][1]);
        o.z = (short)f2bf(acc[m][n][2]);
        o.w = (short)f2bf(acc[m][n][3]);
        *(short4*)(vtout + ((size_t)((bb * 16 + hh) * 64 + d)) * 2048 + tt) = o;
      }
    return;
  }

#pragma unroll
  for (int m = 0; m < 4; m++)
#pragma unroll
    for (int n = 0; n < 4; n++) {
      const int col = bxn * 128 + wc * 64 + n * 16 + c;
#pragma unroll
      for (int r = 0; r < 4; r++) {
        const int row = by * 256 + wr * 64 + m * 16 + g * 4 + r;
        if (OUTMODE != 0)
          ((ushort_t*)Cout)[(size_t)row * N + col] = f2bf(acc[m][n][r]);
        else
          ((float*)Cout)[(size_t)row * N + col] = acc[m][n][r];
      }
    }
}

// ---------------- flash attention, causal, hs=64 (R12, unchanged) ----------
__device__ __forceinline__ void stage_kv(const ushort_t* __restrict__ Kp,
                                         const ushort_t* __restrict__ Vt,
                                         ushort_t* Kl, ushort_t* Vl,
                                         int kb, int wave, int lane) {
  const int C3 = 3072, T = 2048;
#pragma unroll
  for (int j = 0; j < 2; j++) {
    const int rbase = wave * 16 + j * 8;
    const int r = rbase + (lane >> 3);
    const int cbg = ((lane & 7) ^ (r & 7)) << 4;
    const int ldsbase = rbase * 128;
    __builtin_amdgcn_global_load_lds(
        (const AS1 void*)(Kp + (size_t)(kb + r) * C3 + (cbg >> 1)),
        (AS3 void*)((char*)Kl + ldsbase), 16, 0, 0);
    __builtin_amdgcn_global_load_lds(
        (const AS1 void*)(Vt + (size_t)r * T + kb + (cbg >> 1)),
        (AS3 void*)((char*)Vl + ldsbase), 16, 0, 0);
  }
}

__global__ __launch_bounds__(256, 2) void k_attn(const ushort_t* __restrict__ qkv,
                                                 const ushort_t* __restrict__ vt,
                                                 ushort_t* __restrict__ y) {
  const int T = 2048, C3 = 3072, Cc = 1024;
  __shared__ ushort_t Kl[2][64 * 64];
  __shared__ ushort_t Vl[2][64 * 64];

  const int tid = threadIdx.x;
  const int wave = tid >> 6, lane = tid & 63;
  const int l31 = lane & 31, hi = lane >> 5;
  const bool hib = (hi != 0);
  const int swr = (l31 & 7) << 4;
  const int b = blockIdx.z, h = blockIdx.y;
  const int tmap = ((int)blockIdx.x + ((b >> 1) << 3)) & 15;
  const int qi = (b & 1) ? (15 - tmap) : tmap;
  const int qbase = qi * 128 + wave * 32;
  const int q = qbase + l31;

  const size_t base = (size_t)b * T * C3 + h * 64;
  const ushort_t* Q = qkv + base;
  const ushort_t* Kp = qkv + base + 1024;
  const ushort_t* Vt = vt + (size_t)((b * 16 + h) * 64) * T;

  const float KS = 0.125f * 1.44269504f;
  const float THR = 8.0f;

  short8 qfr[4];
  {
    const ushort_t* qp = Q + (size_t)q * C3 + 8 * hi;
#pragma unroll
    for (int i = 0; i < 4; i++) qfr[i] = *(const short8*)(qp + 16 * i);
  }

  f32x16 yacc0 = (f32x16)(0.0f), yacc1 = (f32x16)(0.0f);
  float mx = -3.0e38f, ssum = 0.f;

  const int nk_blk = (qi + 1) * 128;
  stage_kv(Kp, Vt, Kl[0], Vl[0], 0, wave, lane);
  __syncthreads();
  int cur = 0;

  for (int kb = 0; kb < nk_blk; kb += 64) {
    if (kb + 64 < nk_blk)
      stage_kv(Kp, Vt, Kl[cur ^ 1], Vl[cur ^ 1], kb + 64, wave, lane);

    if (kb < qbase + 32) {
      const char* Kbuf = (const char*)Kl[cur];
      const char* Vbuf = (const char*)Vl[cur];

      f32x16 s0 = (f32x16)(0.0f), s1 = (f32x16)(0.0f);
#pragma unroll
      for (int i = 0; i < 4; i++) {
        const int colb = (32 * i + 16 * hi) ^ swr;
        const short8 ka0 = *(const short8*)(Kbuf + l31 * 128 + colb);
        const short8 ka1 = *(const short8*)(Kbuf + (32 + l31) * 128 + colb);
        s0 = __builtin_amdgcn_mfma_f32_32x32x16_bf16(ka0, qfr[i], s0, 0, 0, 0);
        s1 = __builtin_amdgcn_mfma_f32_32x32x16_bf16(ka1, qfr[i], s1, 0, 0, 0);
      }

      if (kb + 63 > qbase) {
#pragma unroll
        for (int r = 0; r < 16; r++) {
          const int key = kb + (r & 3) + 8 * (r >> 2) + 4 * hi;
          if (key > q) s0[r] = -1.0e30f;
          if (key + 32 > q) s1[r] = -1.0e30f;
        }
      }

      float t16[16];
#pragma unroll
      for (int r = 0; r < 16; r++) t16[r] = fmaxf(s0[r], s1[r]);
#pragma unroll
      for (int r = 0; r < 8; r++) t16[r] = fmaxf(t16[r], t16[r + 8]);
#pragma unroll
      for (int r = 0; r < 4; r++) t16[r] = fmaxf(t16[r], t16[r + 4]);
      float tm = fmaxf(fmaxf(t16[0], t16[1]), fmaxf(t16[2], t16[3]));
      tm = fmaxf(tm, __shfl_xor(tm, 32));
      const float cand = tm * KS;

      if (__any(cand > mx + THR)) {
        const float mnew = fmaxf(mx, cand);
        const float alpha = EXP2(mx - mnew);
        ssum *= alpha;
#pragma unroll
        for (int r = 0; r < 16; r++) { yacc0[r] *= alpha; yacc1[r] *= alpha; }
        mx = mnew;
      }

#pragma unroll
      for (int r = 0; r < 16; r++) {
        s0[r] = EXP2(__builtin_fmaf(s0[r], KS, -mx));
        s1[r] = EXP2(__builtin_fmaf(s1[r], KS, -mx));
      }
      {
        float ss[16];
#pragma unroll
        for (int r = 0; r < 16; r++) ss[r] = s0[r] + s1[r];
#pragma unroll
        for (int r = 0; r < 8; r++) ss[r] += ss[r + 8];
#pragma unroll
        for (int r = 0; r < 4; r++) ss[r] += ss[r + 4];
        float ts = (ss[0] + ss[1]) + (ss[2] + ss[3]);
        ts += __shfl_xor(ts, 32);
        ssum += ts;
      }

      union U4 { unsigned u[4]; short8 v; };
      U4 pb[4];
      {
        unsigned dw[4][4];
#pragma unroll
        for (int j = 0; j < 2; j++) {
          dw[j][0] = cvt_pk_bf16(s0[j * 8 + 0], s0[j * 8 + 1]);
          dw[j][1] = cvt_pk_bf16(s0[j * 8 + 2], s0[j * 8 + 3]);
          dw[j][2] = cvt_pk_bf16(s0[j * 8 + 4], s0[j * 8 + 5]);
          dw[j][3] = cvt_pk_bf16(s0[j * 8 + 6], s0[j * 8 + 7]);
          dw[2 + j][0] = cvt_pk_bf16(s1[j * 8 + 0], s1[j * 8 + 1]);
          dw[2 + j][1] = cvt_pk_bf16(s1[j * 8 + 2], s1[j * 8 + 3]);
          dw[2 + j][2] = cvt_pk_bf16(s1[j * 8 + 4], s1[j * 8 + 5]);
          dw[2 + j][3] = cvt_pk_bf16(s1[j * 8 + 6], s1[j * 8 + 7]);
        }
#pragma unroll
        for (int j = 0; j < 4; j++) {
          const unsigned d0 = dw[j][0], d1 = dw[j][1], d2 = dw[j][2], d3 = dw[j][3];
          const unsigned snd0 = hib ? d0 : d2;
          const unsigned snd1 = hib ? d1 : d3;
          const unsigned rcv0 = (unsigned)__shfl_xor((int)snd0, 32);
          const unsigned rcv1 = (unsigned)__shfl_xor((int)snd1, 32);
          pb[j].u[0] = hib ? rcv0 : d0;
          pb[j].u[1] = hib ? rcv1 : d1;
          pb[j].u[2] = hib ? d2 : rcv0;
          pb[j].u[3] = hib ? d3 : rcv1;
        }
      }

#pragma unroll
      for (int sj = 0; sj < 4; sj++) {
        const int colb = (sj * 32 + 16 * hi) ^ swr;
        const short8 va0 = *(const short8*)(Vbuf + l31 * 128 + colb);
        const short8 va1 = *(const short8*)(Vbuf + (32 + l31) * 128 + colb);
        yacc0 = __builtin_amdgcn_mfma_f32_32x32x16_bf16(va0, pb[sj].v, yacc0, 0, 0, 0);
        yacc1 = __builtin_amdgcn_mfma_f32_32x32x16_bf16(va1, pb[sj].v, yacc1, 0, 0, 0);
      }
    }

    __syncthreads();
    cur ^= 1;
  }

  const float inv = 1.0f / ssum;
  ushort_t* yp = y + (size_t)(b * T + q) * Cc + h * 64;
#pragma unroll
  for (int gi = 0; gi < 4; gi++) {
    short4 o0, o1;
    o0.x = (short)f2bf(yacc0[gi * 4 + 0] * inv);
    o0.y = (short)f2bf(yacc0[gi * 4 + 1] * inv);
    o0.z = (short)f2bf(yacc0[gi * 4 + 2] * inv);
    o0.w = (short)f2bf(yacc0[gi * 4 + 3] * inv);
    o1.x = (short)f2bf(yacc1[gi * 4 + 0] * inv);
    o1.y = (short)f2bf(yacc1[gi * 4 + 1] * inv);
    o1.z = (short)f2bf(yacc1[gi * 4 + 2] * inv);
    o1.w = (short)f2bf(yacc1[gi * 4 + 3] * inv);
    *(short4*)(yp + 8 * gi + 4 * hi) = o0;
    *(short4*)(yp + 32 + 8 * gi + 4 * hi) = o1;
  }
}

// ---------------------------------------------------------------------------
extern "C" void kernel_launch(void* const* d_in, const int* in_sizes, int n_in,
                              void* d_out, int out_size, void* d_ws, size_t ws_size,
                              hipStream_t stream) {
  const float* x = (const float*)d_in[0];     // (4, 2048, 1024)
  const float* Wat = (const float*)d_in[1];   // (1024, 3072)
  const float* Wpr = (const float*)d_in[2];   // (1024, 1024)
  float* out = (float*)d_out;                 // (4, 2048, 1024)

  const int T = 2048, B = 4, H = 16, Cc = 1024;
  const int M = B * T;  // 8192

  char* ws = (char*)d_ws;
  const size_t MB = 1024 * 1024;
  ushort_t* xb = (ushort_t*)ws;                 // 16 MB
  ushort_t* wat = (ushort_t*)(ws + 16 * MB);    // 6 MB
  ushort_t* wpt = (ushort_t*)(ws + 24 * MB);    // 2 MB
  ushort_t* qkv = (ushort_t*)(ws + 32 * MB);    // 48 MB
  ushort_t* yb = (ushort_t*)(ws + 80 * MB);     // 16 MB

  const bool big_ws = (ws_size >= (size_t)112 * MB);  // proven true in R11

  // 1. convert inputs to bf16 (weights transposed to [N][K])
  k_f32_to_bf16<<<dim3((M * Cc) / (8 * 256)), 256, 0, stream>>>(x, xb);
  k_transpose_bf16<<<dim3(3072 / 32, 1024 / 32), 256, 0, stream>>>(Wat, wat, 1024, 3072);
  k_transpose_bf16<<<dim3(1024 / 32, 1024 / 32), 256, 0, stream>>>(Wpr, wpt, 1024, 1024);

  if (big_ws) {
    ushort_t* vtb = (ushort_t*)(ws + 96 * MB);  // 16 MB
    // 2. qkv = x @ W_attn (Q,K cols -> qkv; V cols -> Vt transposed, fused)
    k_gemm256<2><<<dim3(3072 / 128, M / 256), 512, 0, stream>>>(xb, wat, qkv, vtb, 3072, 1024);
    // 3. causal flash attention -> y
    k_attn<<<dim3(16, H, B), 256, 0, stream>>>(qkv, vtb, yb);
  } else {
    // Fallback: plain GEMM1 + separate V-transpose (Vt reuses xb, dead after GEMM1)
    ushort_t* vtb = xb;
    k_gemm256<1><<<dim3(3072 / 128, M / 256), 512, 0, stream>>>(xb, wat, qkv, nullptr, 3072, 1024);
    k_vt<<<dim3(T / 64, H, B), 256, 0, stream>>>(qkv, vtb);
    k_attn<<<dim3(16, H, B), 256, 0, stream>>>(qkv, vtb, yb);
  }

  // 4. out = y @ W_proj   (8192 x 1024, fp32)
  k_gemm256<0><<<dim3(1024 / 128, M / 256), 512, 0, stream>>>(yb, wpt, out, nullptr, 1024, 1024);
}

// Round 14
// 164.998 us; speedup vs baseline: 1.4804x; 1.1063x over previous
//
#include <hip/hip_runtime.h>
#include <hip/hip_bf16.h>
#include <cstdint>
#include <cstddef>

// CausalSelfAttention: B=4, T=2048, C=1024, H=16, hs=64 (fp32 in/out, bf16 MFMA compute)
//
// Pipeline: x->bf16 | W^T bf16 | GEMM1 (qkv; V written transposed in epilogue)
//           | flash attn (32x32 MFMA, swapped operands) | GEMM2
//
// GEMM = 3-deep counted-vmcnt pipeline (T3+T4) + XOR-swizzled LDS (T2) +
// setprio (T5). R14: single-phase tile — all 16 ds_reads issued up front,
// one MFMA cluster, ONE barrier + one counted vmcnt per K-tile (was 5
// barriers). Per-wave lgkmcnt staggers waves into MFMA; cross-wave
// ds_read||MFMA overlap replaces barrier lockstep.
//
// Workspace (needs 112 MiB; proven available in R11):
//   [0,16M)    x_bf16 | [16M,22M) W_attn^T | [24M,26M) W_proj^T
//   [32M,80M)  qkv bf16 | [80M,96M) y bf16 | [96M,112M) Vt[b][h][64][2048]

typedef unsigned short ushort_t;
typedef __attribute__((ext_vector_type(8))) short short8;
typedef __attribute__((ext_vector_type(4))) float f32x4;
typedef __attribute__((ext_vector_type(16))) float f32x16;

#define AS1 __attribute__((address_space(1)))
#define AS3 __attribute__((address_space(3)))

#if __has_builtin(__builtin_amdgcn_exp2f)
#define EXP2(x) __builtin_amdgcn_exp2f(x)
#else
#define EXP2(x) exp2f(x)
#endif

__device__ __forceinline__ ushort_t f2bf(float f) {
  union { float f; unsigned u; } c; c.f = f;
  unsigned u = c.u;
  return (ushort_t)((u + 0x7FFFu + ((u >> 16) & 1u)) >> 16);  // RNE
}

__device__ __forceinline__ unsigned cvt_pk_bf16(float a, float b) {
  unsigned r;
  asm("v_cvt_pk_bf16_f32 %0, %1, %2" : "=v"(r) : "v"(a), "v"(b));
  return r;
}

// ---------------- fp32 -> bf16 elementwise (8 elems/thread) ----------------
__global__ __launch_bounds__(256) void k_f32_to_bf16(const float* __restrict__ in,
                                                     ushort_t* __restrict__ out) {
  const size_t i = ((size_t)blockIdx.x * 256 + threadIdx.x) * 8;
  f32x4 a = *(const f32x4*)(in + i);
  f32x4 b = *(const f32x4*)(in + i + 4);
  short8 o;
  o[0] = (short)f2bf(a[0]); o[1] = (short)f2bf(a[1]);
  o[2] = (short)f2bf(a[2]); o[3] = (short)f2bf(a[3]);
  o[4] = (short)f2bf(b[0]); o[5] = (short)f2bf(b[1]);
  o[6] = (short)f2bf(b[2]); o[7] = (short)f2bf(b[3]);
  *(short8*)(out + i) = o;
}

// ------------- fp32 (R x C) -> bf16 transposed (C x R), LDS-tiled ----------
__global__ __launch_bounds__(256) void k_transpose_bf16(const float* __restrict__ in,
                                                        ushort_t* __restrict__ out,
                                                        int R, int C) {
  __shared__ float tile[32][33];
  const int tx = threadIdx.x & 31, ty = threadIdx.x >> 5;  // 32x8
  const int c0 = blockIdx.x * 32, r0 = blockIdx.y * 32;
#pragma unroll
  for (int i = 0; i < 32; i += 8)
    tile[ty + i][tx] = in[(size_t)(r0 + ty + i) * C + c0 + tx];
  __syncthreads();
#pragma unroll
  for (int i = 0; i < 32; i += 8)
    out[(size_t)(c0 + ty + i) * R + r0 + tx] = f2bf(tile[tx][ty + i]);
}

// ---- V transpose (fallback only): qkv V-section -> Vt[b][h][d][t] ----
__global__ __launch_bounds__(256) void k_vt(const ushort_t* __restrict__ qkv,
                                            ushort_t* __restrict__ vt) {
  __shared__ ushort_t tl[64][72];
  const int T = 2048, C3 = 3072;
  const int t0 = blockIdx.x * 64, h = blockIdx.y, b = blockIdx.z;
  const int r = threadIdx.x >> 4;
  const int c4 = (threadIdx.x & 15) * 4;
  const ushort_t* src = qkv + (size_t)(b * T + t0) * C3 + 2048 + h * 64;
#pragma unroll
  for (int p = 0; p < 4; p++) {
    const int row = p * 16 + r;
    *(short4*)&tl[row][c4] = *(const short4*)(src + (size_t)row * C3 + c4);
  }
  __syncthreads();
  ushort_t* dst = vt + (size_t)((b * 16 + h) * 64) * T + t0;
#pragma unroll
  for (int p = 0; p < 4; p++) {
    const int d = p * 16 + r;
    short4 o;
    o.x = (short)tl[c4 + 0][d];
    o.y = (short)tl[c4 + 1][d];
    o.z = (short)tl[c4 + 2][d];
    o.w = (short)tl[c4 + 3][d];
    *(short4*)(dst + (size_t)d * T + c4) = o;
  }
}

// ---- stage one 128x64 bf16 unit: global (row-stride K) -> LDS, swizzled ----
// LDS row r holds global 16B-block u at slot u^(r&7); reads XOR ((r&7)<<4).
__device__ __forceinline__ void stage_unit(const ushort_t* __restrict__ X, int K,
                                           char* ldsbase, int tid, int w) {
#pragma unroll
  for (int j = 0; j < 2; j++) {
    const int rl = j * 64 + (tid >> 3);
    const int gc = ((tid & 7) ^ (rl & 7)) << 3;  // pre-swizzled col (elems)
    __builtin_amdgcn_global_load_lds(
        (const AS1 void*)(X + (size_t)rl * K + gc),
        (AS3 void*)(ldsbase + (j * 64 + w * 8) * 128), 16, 0, 0);
  }
}

// ---------------- bf16 GEMM: C[M,N] = A[M,K] * Bt[N,K]^T -------------------
// BM=256, BN=128, BK=64; 512 threads = 8 waves (4M x 2N), per-wave 64x64 out.
// 3 LDS buffers (144KB): compute tile t from buf[t%3] while tile t+2 stages
// into buf[(t+2)%3]; ONE boundary s_waitcnt vmcnt(6) + s_barrier per tile.
// All 16 ds_reads issued before the 32-MFMA cluster: compiler lgkmcnt(8)/(0)
// staggers each wave, cross-wave ds_read||MFMA overlap does the pipelining.
// OUTMODE: 0 = fp32 C; 1 = bf16 C; 2 = bf16 C for cols<2048 + fused
// V-transpose (cols>=2048 -> Vt[b][h][d][t]).
template <int OUTMODE>
__global__ __launch_bounds__(512, 2) void k_gemm256(const ushort_t* __restrict__ A,
                                                    const ushort_t* __restrict__ Bt,
                                                    void* __restrict__ Cout,
                                                    ushort_t* __restrict__ vtout,
                                                    int N, int K) {
  __shared__ ushort_t As[3 * 256 * 64];  // 96KB: 3 bufs x [256][64]
  __shared__ ushort_t Bs[3 * 128 * 64];  // 48KB: 3 bufs x [128][64]

  const int tid = threadIdx.x;
  const int w = tid >> 6, lane = tid & 63;
  const int c = lane & 15, g = lane >> 4;
  const int wr = w >> 1, wc = w & 1;

  // bijective XCD swizzle (nwg % 8 == 0 for all our launches)
  const int nwg = gridDim.x * gridDim.y;
  int wg = blockIdx.y * gridDim.x + blockIdx.x;
  {
    const int qd = nwg >> 3, rm = nwg & 7;
    const int xcd = wg & 7, idx = wg >> 3;
    wg = (xcd < rm ? xcd * (qd + 1) : rm * (qd + 1) + (xcd - rm) * qd) + idx;
  }
  const int bxn = wg % gridDim.x, by = wg / gridDim.x;

  const ushort_t* Abase = A + (size_t)(by * 256) * K;
  const ushort_t* Bbase = Bt + (size_t)(bxn * 128) * K;
  const int NT = K >> 6;  // K-tiles (16 for K=1024)

  auto stageT = [&](int tt) {
    const int s = tt % 3, k0 = tt * 64;
    char* Ab = (char*)As + s * 32768;
    char* Bb = (char*)Bs + s * 16384;
    stage_unit(Abase + k0, K, Ab, tid, w);
    stage_unit(Abase + (size_t)128 * K + k0, K, Ab + 16384, tid, w);
    stage_unit(Bbase + k0, K, Bb, tid, w);
  };

  f32x4 acc[4][4];
#pragma unroll
  for (int m = 0; m < 4; m++)
#pragma unroll
    for (int n = 0; n < 4; n++) acc[m][n] = (f32x4){0.f, 0.f, 0.f, 0.f};

  // prologue: stage tiles 0,1; wait tile 0 (tile 1's 6 loads stay in flight)
  stageT(0);
  stageT(1);
  __builtin_amdgcn_sched_barrier(0);
  asm volatile("s_waitcnt vmcnt(6)" ::: "memory");
  __builtin_amdgcn_s_barrier();
  __builtin_amdgcn_sched_barrier(0);

  for (int t = 0; t < NT; ++t) {
    const int cur = t % 3;
    const char* Ab = (const char*)As + cur * 32768;
    const char* Bb = (const char*)Bs + cur * 16384;

    // ---- issue ALL 16 ds_reads (both K-halves), then the prefetch ----
    short8 af0[4], bv0[4], af1[4], bv1[4];
#pragma unroll
    for (int m = 0; m < 4; m++) {
      const int r = wr * 64 + m * 16 + c;
      const int sw = (r & 7) << 4;
      af0[m] = *(const short8*)(Ab + r * 128 + ((g * 16) ^ sw));
      af1[m] = *(const short8*)(Ab + r * 128 + ((64 + g * 16) ^ sw));
    }
#pragma unroll
    for (int n = 0; n < 4; n++) {
      const int r = wc * 64 + n * 16 + c;
      const int sw = (r & 7) << 4;
      bv0[n] = *(const short8*)(Bb + r * 128 + ((g * 16) ^ sw));
      bv1[n] = *(const short8*)(Bb + r * 128 + ((64 + g * 16) ^ sw));
    }
    if (t + 2 < NT) stageT(t + 2);  // into buf[(t+2)%3]: all reads of that
                                    // buf drained before last barrier

    // ---- 32-MFMA cluster (lgkmcnt auto-staggers waves) ----
    __builtin_amdgcn_s_setprio(1);
#pragma unroll
    for (int m = 0; m < 4; m++)
#pragma unroll
      for (int n = 0; n < 4; n++)
        acc[m][n] = __builtin_amdgcn_mfma_f32_16x16x32_bf16(af0[m], bv0[n], acc[m][n], 0, 0, 0);
#pragma unroll
    for (int m = 0; m < 4; m++)
#pragma unroll
      for (int n = 0; n < 4; n++)
        acc[m][n] = __builtin_amdgcn_mfma_f32_16x16x32_bf16(af1[m], bv1[n], acc[m][n], 0, 0, 0);
    __builtin_amdgcn_s_setprio(0);

    // ---- tile boundary: tile t+1 staged for ALL waves; t+2 stays in flight --
    if (t + 1 < NT) {
      __builtin_amdgcn_sched_barrier(0);
      if (t + 2 < NT)
        asm volatile("s_waitcnt vmcnt(6)" ::: "memory");
      else
        asm volatile("s_waitcnt vmcnt(0)" ::: "memory");  // last prefetch: drain
      __builtin_amdgcn_s_barrier();
      __builtin_amdgcn_sched_barrier(0);
    }
  }

  // ---- epilogue ----
  if (OUTMODE == 2 && bxn >= 16) {
    // V columns -> Vt[b][h][d][t]; acc regs r=0..3 are consecutive t.
#pragma unroll
    for (int m = 0; m < 4; m++)
#pragma unroll
      for (int n = 0; n < 4; n++) {
        const int cv = bxn * 128 + wc * 64 + n * 16 + c - 2048;  // 0..1023
        const int hh = cv >> 6, d = cv & 63;
        const int row = by * 256 + wr * 64 + m * 16 + g * 4;
        const int bb = row >> 11, tt = row & 2047;
        short4 o;
        o.x = (short)f2bf(acc[m][n][0]);
        o.y = (short)f2bf(acc[m][n][1]);
        o.z = (short)f2bf(acc[m][n][2]);
        o.w = (short)f2bf(acc[m][n][3]);
        *(short4*)(vtout + ((size_t)((bb * 16 + hh) * 64 + d)) * 2048 + tt) = o;
      }
    return;
  }

#pragma unroll
  for (int m = 0; m < 4; m++)
#pragma unroll
    for (int n = 0; n < 4; n++) {
      const int col = bxn * 128 + wc * 64 + n * 16 + c;
#pragma unroll
      for (int r = 0; r < 4; r++) {
        const int row = by * 256 + wr * 64 + m * 16 + g * 4 + r;
        if (OUTMODE != 0)
          ((ushort_t*)Cout)[(size_t)row * N + col] = f2bf(acc[m][n][r]);
        else
          ((float*)Cout)[(size_t)row * N + col] = acc[m][n][r];
      }
    }
}

// ---------------- flash attention, causal, hs=64 (R12, unchanged) ----------
__device__ __forceinline__ void stage_kv(const ushort_t* __restrict__ Kp,
                                         const ushort_t* __restrict__ Vt,
                                         ushort_t* Kl, ushort_t* Vl,
                                         int kb, int wave, int lane) {
  const int C3 = 3072, T = 2048;
#pragma unroll
  for (int j = 0; j < 2; j++) {
    const int rbase = wave * 16 + j * 8;
    const int r = rbase + (lane >> 3);
    const int cbg = ((lane & 7) ^ (r & 7)) << 4;
    const int ldsbase = rbase * 128;
    __builtin_amdgcn_global_load_lds(
        (const AS1 void*)(Kp + (size_t)(kb + r) * C3 + (cbg >> 1)),
        (AS3 void*)((char*)Kl + ldsbase), 16, 0, 0);
    __builtin_amdgcn_global_load_lds(
        (const AS1 void*)(Vt + (size_t)r * T + kb + (cbg >> 1)),
        (AS3 void*)((char*)Vl + ldsbase), 16, 0, 0);
  }
}

__global__ __launch_bounds__(256, 2) void k_attn(const ushort_t* __restrict__ qkv,
                                                 const ushort_t* __restrict__ vt,
                                                 ushort_t* __restrict__ y) {
  const int T = 2048, C3 = 3072, Cc = 1024;
  __shared__ ushort_t Kl[2][64 * 64];
  __shared__ ushort_t Vl[2][64 * 64];

  const int tid = threadIdx.x;
  const int wave = tid >> 6, lane = tid & 63;
  const int l31 = lane & 31, hi = lane >> 5;
  const bool hib = (hi != 0);
  const int swr = (l31 & 7) << 4;
  const int b = blockIdx.z, h = blockIdx.y;
  const int tmap = ((int)blockIdx.x + ((b >> 1) << 3)) & 15;
  const int qi = (b & 1) ? (15 - tmap) : tmap;
  const int qbase = qi * 128 + wave * 32;
  const int q = qbase + l31;

  const size_t base = (size_t)b * T * C3 + h * 64;
  const ushort_t* Q = qkv + base;
  const ushort_t* Kp = qkv + base + 1024;
  const ushort_t* Vt = vt + (size_t)((b * 16 + h) * 64) * T;

  const float KS = 0.125f * 1.44269504f;
  const float THR = 8.0f;

  short8 qfr[4];
  {
    const ushort_t* qp = Q + (size_t)q * C3 + 8 * hi;
#pragma unroll
    for (int i = 0; i < 4; i++) qfr[i] = *(const short8*)(qp + 16 * i);
  }

  f32x16 yacc0 = (f32x16)(0.0f), yacc1 = (f32x16)(0.0f);
  float mx = -3.0e38f, ssum = 0.f;

  const int nk_blk = (qi + 1) * 128;
  stage_kv(Kp, Vt, Kl[0], Vl[0], 0, wave, lane);
  __syncthreads();
  int cur = 0;

  for (int kb = 0; kb < nk_blk; kb += 64) {
    if (kb + 64 < nk_blk)
      stage_kv(Kp, Vt, Kl[cur ^ 1], Vl[cur ^ 1], kb + 64, wave, lane);

    if (kb < qbase + 32) {
      const char* Kbuf = (const char*)Kl[cur];
      const char* Vbuf = (const char*)Vl[cur];

      f32x16 s0 = (f32x16)(0.0f), s1 = (f32x16)(0.0f);
#pragma unroll
      for (int i = 0; i < 4; i++) {
        const int colb = (32 * i + 16 * hi) ^ swr;
        const short8 ka0 = *(const short8*)(Kbuf + l31 * 128 + colb);
        const short8 ka1 = *(const short8*)(Kbuf + (32 + l31) * 128 + colb);
        s0 = __builtin_amdgcn_mfma_f32_32x32x16_bf16(ka0, qfr[i], s0, 0, 0, 0);
        s1 = __builtin_amdgcn_mfma_f32_32x32x16_bf16(ka1, qfr[i], s1, 0, 0, 0);
      }

      if (kb + 63 > qbase) {
#pragma unroll
        for (int r = 0; r < 16; r++) {
          const int key = kb + (r & 3) + 8 * (r >> 2) + 4 * hi;
          if (key > q) s0[r] = -1.0e30f;
          if (key + 32 > q) s1[r] = -1.0e30f;
        }
      }

      float t16[16];
#pragma unroll
      for (int r = 0; r < 16; r++) t16[r] = fmaxf(s0[r], s1[r]);
#pragma unroll
      for (int r = 0; r < 8; r++) t16[r] = fmaxf(t16[r], t16[r + 8]);
#pragma unroll
      for (int r = 0; r < 4; r++) t16[r] = fmaxf(t16[r], t16[r + 4]);
      float tm = fmaxf(fmaxf(t16[0], t16[1]), fmaxf(t16[2], t16[3]));
      tm = fmaxf(tm, __shfl_xor(tm, 32));
      const float cand = tm * KS;

      if (__any(cand > mx + THR)) {
        const float mnew = fmaxf(mx, cand);
        const float alpha = EXP2(mx - mnew);
        ssum *= alpha;
#pragma unroll
        for (int r = 0; r < 16; r++) { yacc0[r] *= alpha; yacc1[r] *= alpha; }
        mx = mnew;
      }

#pragma unroll
      for (int r = 0; r < 16; r++) {
        s0[r] = EXP2(__builtin_fmaf(s0[r], KS, -mx));
        s1[r] = EXP2(__builtin_fmaf(s1[r], KS, -mx));
      }
      {
        float ss[16];
#pragma unroll
        for (int r = 0; r < 16; r++) ss[r] = s0[r] + s1[r];
#pragma unroll
        for (int r = 0; r < 8; r++) ss[r] += ss[r + 8];
#pragma unroll
        for (int r = 0; r < 4; r++) ss[r] += ss[r + 4];
        float ts = (ss[0] + ss[1]) + (ss[2] + ss[3]);
        ts += __shfl_xor(ts, 32);
        ssum += ts;
      }

      union U4 { unsigned u[4]; short8 v; };
      U4 pb[4];
      {
        unsigned dw[4][4];
#pragma unroll
        for (int j = 0; j < 2; j++) {
          dw[j][0] = cvt_pk_bf16(s0[j * 8 + 0], s0[j * 8 + 1]);
          dw[j][1] = cvt_pk_bf16(s0[j * 8 + 2], s0[j * 8 + 3]);
          dw[j][2] = cvt_pk_bf16(s0[j * 8 + 4], s0[j * 8 + 5]);
          dw[j][3] = cvt_pk_bf16(s0[j * 8 + 6], s0[j * 8 + 7]);
          dw[2 + j][0] = cvt_pk_bf16(s1[j * 8 + 0], s1[j * 8 + 1]);
          dw[2 + j][1] = cvt_pk_bf16(s1[j * 8 + 2], s1[j * 8 + 3]);
          dw[2 + j][2] = cvt_pk_bf16(s1[j * 8 + 4], s1[j * 8 + 5]);
          dw[2 + j][3] = cvt_pk_bf16(s1[j * 8 + 6], s1[j * 8 + 7]);
        }
#pragma unroll
        for (int j = 0; j < 4; j++) {
          const unsigned d0 = dw[j][0], d1 = dw[j][1], d2 = dw[j][2], d3 = dw[j][3];
          const unsigned snd0 = hib ? d0 : d2;
          const unsigned snd1 = hib ? d1 : d3;
          const unsigned rcv0 = (unsigned)__shfl_xor((int)snd0, 32);
          const unsigned rcv1 = (unsigned)__shfl_xor((int)snd1, 32);
          pb[j].u[0] = hib ? rcv0 : d0;
          pb[j].u[1] = hib ? rcv1 : d1;
          pb[j].u[2] = hib ? d2 : rcv0;
          pb[j].u[3] = hib ? d3 : rcv1;
        }
      }

#pragma unroll
      for (int sj = 0; sj < 4; sj++) {
        const int colb = (sj * 32 + 16 * hi) ^ swr;
        const short8 va0 = *(const short8*)(Vbuf + l31 * 128 + colb);
        const short8 va1 = *(const short8*)(Vbuf + (32 + l31) * 128 + colb);
        yacc0 = __builtin_amdgcn_mfma_f32_32x32x16_bf16(va0, pb[sj].v, yacc0, 0, 0, 0);
        yacc1 = __builtin_amdgcn_mfma_f32_32x32x16_bf16(va1, pb[sj].v, yacc1, 0, 0, 0);
      }
    }

    __syncthreads();
    cur ^= 1;
  }

  const float inv = 1.0f / ssum;
  ushort_t* yp = y + (size_t)(b * T + q) * Cc + h * 64;
#pragma unroll
  for (int gi = 0; gi < 4; gi++) {
    short4 o0, o1;
    o0.x = (short)f2bf(yacc0[gi * 4 + 0] * inv);
    o0.y = (short)f2bf(yacc0[gi * 4 + 1] * inv);
    o0.z = (short)f2bf(yacc0[gi * 4 + 2] * inv);
    o0.w = (short)f2bf(yacc0[gi * 4 + 3] * inv);
    o1.x = (short)f2bf(yacc1[gi * 4 + 0] * inv);
    o1.y = (short)f2bf(yacc1[gi * 4 + 1] * inv);
    o1.z = (short)f2bf(yacc1[gi * 4 + 2] * inv);
    o1.w = (short)f2bf(yacc1[gi * 4 + 3] * inv);
    *(short4*)(yp + 8 * gi + 4 * hi) = o0;
    *(short4*)(yp + 32 + 8 * gi + 4 * hi) = o1;
  }
}

// ---------------------------------------------------------------------------
extern "C" void kernel_launch(void* const* d_in, const int* in_sizes, int n_in,
                              void* d_out, int out_size, void* d_ws, size_t ws_size,
                              hipStream_t stream) {
  const float* x = (const float*)d_in[0];     // (4, 2048, 1024)
  const float* Wat = (const float*)d_in[1];   // (1024, 3072)
  const float* Wpr = (const float*)d_in[2];   // (1024, 1024)
  float* out = (float*)d_out;                 // (4, 2048, 1024)

  const int T = 2048, B = 4, H = 16, Cc = 1024;
  const int M = B * T;  // 8192

  char* ws = (char*)d_ws;
  const size_t MB = 1024 * 1024;
  ushort_t* xb = (ushort_t*)ws;                 // 16 MB
  ushort_t* wat = (ushort_t*)(ws + 16 * MB);    // 6 MB
  ushort_t* wpt = (ushort_t*)(ws + 24 * MB);    // 2 MB
  ushort_t* qkv = (ushort_t*)(ws + 32 * MB);    // 48 MB
  ushort_t* yb = (ushort_t*)(ws + 80 * MB);     // 16 MB

  const bool big_ws = (ws_size >= (size_t)112 * MB);  // proven true in R11

  // 1. convert inputs to bf16 (weights transposed to [N][K])
  k_f32_to_bf16<<<dim3((M * Cc) / (8 * 256)), 256, 0, stream>>>(x, xb);
  k_transpose_bf16<<<dim3(3072 / 32, 1024 / 32), 256, 0, stream>>>(Wat, wat, 1024, 3072);
  k_transpose_bf16<<<dim3(1024 / 32, 1024 / 32), 256, 0, stream>>>(Wpr, wpt, 1024, 1024);

  if (big_ws) {
    ushort_t* vtb = (ushort_t*)(ws + 96 * MB);  // 16 MB
    // 2. qkv = x @ W_attn (Q,K cols -> qkv; V cols -> Vt transposed, fused)
    k_gemm256<2><<<dim3(3072 / 128, M / 256), 512, 0, stream>>>(xb, wat, qkv, vtb, 3072, 1024);
    // 3. causal flash attention -> y
    k_attn<<<dim3(16, H, B), 256, 0, stream>>>(qkv, vtb, yb);
  } else {
    // Fallback: plain GEMM1 + separate V-transpose (Vt reuses xb, dead after GEMM1)
    ushort_t* vtb = xb;
    k_gemm256<1><<<dim3(3072 / 128, M / 256), 512, 0, stream>>>(xb, wat, qkv, nullptr, 3072, 1024);
    k_vt<<<dim3(T / 64, H, B), 256, 0, stream>>>(qkv, vtb);
    k_attn<<<dim3(16, H, B), 256, 0, stream>>>(qkv, vtb, yb);
  }

  // 4. out = y @ W_proj   (8192 x 1024, fp32)
  k_gemm256<0><<<dim3(1024 / 128, M / 256), 512, 0, stream>>>(yb, wpt, out, nullptr, 1024, 1024);
}